// Round 1
// baseline (580.558 us; speedup 1.0000x reference)
//
#include <hip/hip_runtime.h>
#include <cstdint>
#include <cstddef>

// ---------------- types ----------------
typedef __bf16 bf16x8 __attribute__((ext_vector_type(8)));
typedef float  floatx4 __attribute__((ext_vector_type(4)));
typedef unsigned short ushortx8 __attribute__((ext_vector_type(8)));
typedef unsigned short ushortx4 __attribute__((ext_vector_type(4)));

#define MFMA16(a, b, c) __builtin_amdgcn_mfma_f32_16x16x32_bf16((a), (b), (c), 0, 0, 0)

__device__ inline unsigned short f2bf(float f) {
    // round-to-nearest-even f32 -> bf16 (finite inputs only)
    unsigned int u = __float_as_uint(f);
    unsigned int r = (u + 0x7fffu + ((u >> 16) & 1u)) >> 16;
    return (unsigned short)r;
}

// ---------------- fp32 -> bf16 convert ----------------
__global__ __launch_bounds__(256) void k_f32_to_bf16(const float* __restrict__ src,
                                                     unsigned short* __restrict__ dst,
                                                     int n8) {
    int i = blockIdx.x * 256 + threadIdx.x;  // each thread: 8 elements
    if (i >= n8) return;
    const float4* s = (const float4*)src + (size_t)i * 2;
    float4 x0 = s[0], x1 = s[1];
    ushortx8 o;
    o[0] = f2bf(x0.x); o[1] = f2bf(x0.y); o[2] = f2bf(x0.z); o[3] = f2bf(x0.w);
    o[4] = f2bf(x1.x); o[5] = f2bf(x1.y); o[6] = f2bf(x1.z); o[7] = f2bf(x1.w);
    *((ushortx8*)dst + i) = o;
}

// ---------------- GEMM: C[M][Nc] = A[M][K](bf16) @ W[Nc][K]^T(bf16) + bias ----------------
// 128x128 tile, BK=32, 256 threads = 4 waves in 2x2. Register prefetch of next K-tile.
__global__ __launch_bounds__(256) void k_gemm_bias(const unsigned short* __restrict__ A,
                                                   const unsigned short* __restrict__ W,
                                                   const float* __restrict__ bias,
                                                   void* __restrict__ out,
                                                   int M, int Nc, int K, int out_f32) {
    __shared__ __align__(16) unsigned short As[128 * 32];  // 8 KB
    __shared__ __align__(16) unsigned short Bs[128 * 32];  // 8 KB
    const int tid = threadIdx.x;
    const int wave = tid >> 6, lane = tid & 63;
    const int quad = lane >> 4, l15 = lane & 15;
    const int wm = wave >> 1, wn = wave & 1;
    const int m0 = blockIdx.x * 128, n0 = blockIdx.y * 128;

    const size_t rowbytes = (size_t)K * 2;
    const int idx0 = tid, idx1 = 256 + tid;  // 512 chunks of 16B per tile
    const int rA0 = idx0 >> 2, cb0 = (idx0 & 3) << 4;
    const int rA1 = idx1 >> 2, cb1 = (idx1 & 3) << 4;
    const char* gA0 = (const char*)A + (size_t)(m0 + rA0) * rowbytes + cb0;
    const char* gA1 = (const char*)A + (size_t)(m0 + rA1) * rowbytes + cb1;
    const char* gB0 = (const char*)W + (size_t)(n0 + rA0) * rowbytes + cb0;
    const char* gB1 = (const char*)W + (size_t)(n0 + rA1) * rowbytes + cb1;

    int4 pa0 = *(const int4*)gA0, pa1 = *(const int4*)gA1;
    int4 pb0 = *(const int4*)gB0, pb1 = *(const int4*)gB1;

    floatx4 acc[4][4] = {};

    const int KT = K >> 5;
    for (int kt = 0; kt < KT; ++kt) {
        __syncthreads();
        ((int4*)As)[idx0] = pa0; ((int4*)As)[idx1] = pa1;
        ((int4*)Bs)[idx0] = pb0; ((int4*)Bs)[idx1] = pb1;
        __syncthreads();
        if (kt + 1 < KT) {  // prefetch next K-tile (overlaps with MFMA below)
            gA0 += 64; gA1 += 64; gB0 += 64; gB1 += 64;
            pa0 = *(const int4*)gA0; pa1 = *(const int4*)gA1;
            pb0 = *(const int4*)gB0; pb1 = *(const int4*)gB1;
        }
        bf16x8 af[4], bfr[4];
        const char* Asb = (const char*)As;
        const char* Bsb = (const char*)Bs;
#pragma unroll
        for (int r = 0; r < 4; ++r)
            af[r] = *(const bf16x8*)(Asb + ((wm * 64 + r * 16 + l15) * 64 + quad * 16));
#pragma unroll
        for (int c = 0; c < 4; ++c)
            bfr[c] = *(const bf16x8*)(Bsb + ((wn * 64 + c * 16 + l15) * 64 + quad * 16));
#pragma unroll
        for (int r = 0; r < 4; ++r)
#pragma unroll
            for (int c = 0; c < 4; ++c)
                acc[r][c] = MFMA16(af[r], bfr[c], acc[r][c]);
    }

    // epilogue: C row = quad*4+i, col = l15  (verified m89/m91 C/D layout)
#pragma unroll
    for (int c = 0; c < 4; ++c) {
        int n = n0 + wn * 64 + c * 16 + l15;
        float bv = bias[n];
#pragma unroll
        for (int r = 0; r < 4; ++r) {
            int mrow = m0 + wm * 64 + r * 16 + quad * 4;
#pragma unroll
            for (int i = 0; i < 4; ++i) {
                float v = acc[r][c][i] + bv;
                if (out_f32)
                    ((float*)out)[(size_t)(mrow + i) * Nc + n] = v;
                else
                    ((unsigned short*)out)[(size_t)(mrow + i) * Nc + n] = f2bf(v);
            }
        }
    }
}

// ---------------- per-head transpose: V[4096][1024] -> Vt[b][h][64][1024] ----------------
__global__ __launch_bounds__(256) void k_transpose_v(const unsigned short* __restrict__ V,
                                                     unsigned short* __restrict__ Vt) {
    __shared__ unsigned short tile[64][65];
    int tt = blockIdx.x, h = blockIdx.y, b = blockIdx.z;
    int tid = threadIdx.x;
    int r = tid >> 2, cs = (tid & 3) << 4;
    const unsigned short* src = V + ((size_t)(b * 1024 + tt * 64 + r)) * 1024 + h * 64 + cs;
#pragma unroll
    for (int i = 0; i < 16; ++i) tile[r][cs + i] = src[i];
    __syncthreads();
    int d = tid >> 2, ts = (tid & 3) << 4;
    unsigned short* dst = Vt + ((size_t)(b * 16 + h) * 64 + d) * 1024 + tt * 64 + ts;
#pragma unroll
    for (int i = 0; i < 16; ++i) dst[i] = tile[ts + i][d];
}

// ---------------- flash attention ----------------
// Q,K: [N*L][1024] bf16 channel-major; Vt: [N][H][64][L] bf16; mask: [N][L] float.
// Block: (q-tile 64, h, b); wave handles 16 q rows. TK=32 k-cols per iteration.
__global__ __launch_bounds__(256) void k_flash_attn(const unsigned short* __restrict__ Q,
                                                    const unsigned short* __restrict__ Kb,
                                                    const unsigned short* __restrict__ Vt,
                                                    const float* __restrict__ mask,
                                                    float* __restrict__ ctx,
                                                    int causal) {
    const int L = 1024, D = 1024;
    int qi = blockIdx.x, h = blockIdx.y, b = blockIdx.z;
    int tid = threadIdx.x;
    int wave = tid >> 6, lane = tid & 63, quad = lane >> 4, l15 = lane & 15;
    int qbase = qi * 64 + wave * 16;

    __shared__ __align__(16) unsigned short Plds[4][512];  // per-wave 16x32 bf16

    // Q fragments (A-operand layout: m=l15, k=quad*8+j) read direct from global
    const unsigned short* Qh = Q + ((size_t)(b * L + qbase)) * D + h * 64;
    bf16x8 qf0 = *(const bf16x8*)(Qh + (size_t)l15 * D + quad * 8);
    bf16x8 qf1 = *(const bf16x8*)(Qh + (size_t)l15 * D + 32 + quad * 8);

    floatx4 O[4] = {};                       // O[f][i]: row=quad*4+i, col=f*16+l15
    float mrun[4] = {-1e30f, -1e30f, -1e30f, -1e30f};
    float lrun[4] = {0.f, 0.f, 0.f, 0.f};

    const unsigned short* Kh = Kb + ((size_t)b * L) * D + h * 64;
    const unsigned short* Vh = Vt + ((size_t)(b * 16 + h)) * 64 * 1024;
    const float* mk = mask + b * L;

    int ktiles = causal ? (qi * 2 + 2) : (L / 32);
    for (int kt = 0; kt < ktiles; ++kt) {
        int k0 = kt * 32;
        // S = Q @ K^T for 16 q x 32 k
        floatx4 S0 = {}, S1 = {};
        {
            const unsigned short* Kp0 = Kh + (size_t)(k0 + l15) * D;
            bf16x8 kf0 = *(const bf16x8*)(Kp0 + quad * 8);
            bf16x8 kf1 = *(const bf16x8*)(Kp0 + 32 + quad * 8);
            S0 = MFMA16(qf0, kf0, S0);
            S0 = MFMA16(qf1, kf1, S0);
            const unsigned short* Kp1 = Kh + (size_t)(k0 + 16 + l15) * D;
            bf16x8 kf2 = *(const bf16x8*)(Kp1 + quad * 8);
            bf16x8 kf3 = *(const bf16x8*)(Kp1 + 32 + quad * 8);
            S1 = MFMA16(qf0, kf2, S1);
            S1 = MFMA16(qf1, kf3, S1);
        }
        // scale + mask  (scores/8 + (1-m)*(-1e4); causal: m *= (kcol<=q))
        float m0v = mk[k0 + l15];
        float m1v = mk[k0 + 16 + l15];
        float pen0 = (1.0f - m0v) * -10000.0f;
        float pen1 = (1.0f - m1v) * -10000.0f;
        float sv0[4], sv1[4];
#pragma unroll
        for (int i = 0; i < 4; ++i) {
            int q = qbase + quad * 4 + i;
            float a0 = S0[i] * 0.125f, a1 = S1[i] * 0.125f;
            if (causal) {
                a0 += ((k0 + l15) <= q) ? pen0 : -10000.0f;
                a1 += ((k0 + 16 + l15) <= q) ? pen1 : -10000.0f;
            } else {
                a0 += pen0;
                a1 += pen1;
            }
            sv0[i] = a0;
            sv1[i] = a1;
        }
        // online softmax per row (16-lane butterfly within quad group)
#pragma unroll
        for (int i = 0; i < 4; ++i) {
            float t = fmaxf(sv0[i], sv1[i]);
            t = fmaxf(t, __shfl_xor(t, 1));
            t = fmaxf(t, __shfl_xor(t, 2));
            t = fmaxf(t, __shfl_xor(t, 4));
            t = fmaxf(t, __shfl_xor(t, 8));
            float mnew = fmaxf(mrun[i], t);
            float alpha = __expf(mrun[i] - mnew);
            mrun[i] = mnew;
            float p0 = __expf(sv0[i] - mnew);
            float p1 = __expf(sv1[i] - mnew);
            float rs = p0 + p1;
            rs += __shfl_xor(rs, 1);
            rs += __shfl_xor(rs, 2);
            rs += __shfl_xor(rs, 4);
            rs += __shfl_xor(rs, 8);
            lrun[i] = lrun[i] * alpha + rs;
#pragma unroll
            for (int f = 0; f < 4; ++f) O[f][i] *= alpha;
            sv0[i] = p0;
            sv1[i] = p1;
        }
        // P: C-layout -> A-layout via per-wave LDS round trip
        __syncthreads();
#pragma unroll
        for (int i = 0; i < 4; ++i) {
            Plds[wave][(quad * 4 + i) * 32 + l15] = f2bf(sv0[i]);
            Plds[wave][(quad * 4 + i) * 32 + 16 + l15] = f2bf(sv1[i]);
        }
        __syncthreads();
        bf16x8 pa = *(const bf16x8*)(&Plds[wave][l15 * 32 + quad * 8]);
        // O += P @ V  (B-frag = rows of Vt, contiguous along k)
#pragma unroll
        for (int f = 0; f < 4; ++f) {
            bf16x8 vf = *(const bf16x8*)(Vh + (size_t)(f * 16 + l15) * 1024 + k0 + quad * 8);
            O[f] = MFMA16(pa, vf, O[f]);
        }
    }
    // epilogue: ctx = O / l
#pragma unroll
    for (int i = 0; i < 4; ++i) {
        float inv = 1.0f / lrun[i];
        int q = qbase + quad * 4 + i;
        float* op = ctx + ((size_t)(b * L + q)) * D + h * 64;
#pragma unroll
        for (int f = 0; f < 4; ++f) op[f * 16 + l15] = O[f][i] * inv;
    }
}

// ---------------- add + layernorm (one block per 1024-row) ----------------
__global__ __launch_bounds__(256) void k_add_ln(const float* __restrict__ X,
                                                const float* __restrict__ Y,
                                                const float* __restrict__ w,
                                                const float* __restrict__ bvec,
                                                float* __restrict__ outf,
                                                unsigned short* __restrict__ outbf) {
    int row = blockIdx.x;
    int tid = threadIdx.x;
    float4 x = *((const float4*)(X + (size_t)row * 1024) + tid);
    float4 y = *((const float4*)(Y + (size_t)row * 1024) + tid);
    float v0 = x.x + y.x, v1 = x.y + y.y, v2 = x.z + y.z, v3 = x.w + y.w;
    float s = v0 + v1 + v2 + v3;
    float s2 = v0 * v0 + v1 * v1 + v2 * v2 + v3 * v3;
#pragma unroll
    for (int off = 32; off > 0; off >>= 1) {
        s += __shfl_xor(s, off);
        s2 += __shfl_xor(s2, off);
    }
    __shared__ float red[8];
    int wave = tid >> 6, lane = tid & 63;
    if (lane == 0) { red[wave] = s; red[4 + wave] = s2; }
    __syncthreads();
    s = red[0] + red[1] + red[2] + red[3];
    s2 = red[4] + red[5] + red[6] + red[7];
    float u = s * (1.0f / 1024.0f);
    float var = s2 * (1.0f / 1024.0f) - u * u;
    float r = 1.0f / sqrtf(fmaxf(var, 0.0f) + 1e-12f);
    float4 wv = *((const float4*)w + tid);
    float4 bv = *((const float4*)bvec + tid);
    float o0 = wv.x * (v0 - u) * r + bv.x;
    float o1 = wv.y * (v1 - u) * r + bv.y;
    float o2 = wv.z * (v2 - u) * r + bv.z;
    float o3 = wv.w * (v3 - u) * r + bv.w;
    float4 o = {o0, o1, o2, o3};
    *((float4*)(outf + (size_t)row * 1024) + tid) = o;
    if (outbf) {
        ushortx4 ob;
        ob[0] = f2bf(o0); ob[1] = f2bf(o1); ob[2] = f2bf(o2); ob[3] = f2bf(o3);
        *((ushortx4*)outbf + (size_t)row * 256 + tid) = ob;
    }
}

// ---------------- host ----------------
extern "C" void kernel_launch(void* const* d_in, const int* in_sizes, int n_in,
                              void* d_out, int out_size, void* d_ws, size_t ws_size,
                              hipStream_t stream) {
    (void)in_sizes; (void)n_in; (void)out_size; (void)ws_size;
    const float* dec = (const float*)d_in[0];
    const float* enc = (const float*)d_in[1];
    const float* dec_mask = (const float*)d_in[2];
    const float* enc_mask = (const float*)d_in[3];
    // weights in dict order: sa_qw, sa_kw, sa_vw, ca_qw, ca_kw, ca_vw, out_w
    const float* Wsrc[7];
    for (int i = 0; i < 7; ++i) Wsrc[i] = (const float*)d_in[4 + i];
    const float* b_saq = (const float*)d_in[11];
    const float* b_sak = (const float*)d_in[12];
    const float* b_sav = (const float*)d_in[13];
    const float* b_caq = (const float*)d_in[14];
    const float* b_cak = (const float*)d_in[15];
    const float* b_cav = (const float*)d_in[16];
    const float* b_out = (const float*)d_in[17];
    const float* n1_b = (const float*)d_in[18];
    const float* n2_b = (const float*)d_in[19];
    const float* oln_b = (const float*)d_in[20];
    const float* n1_w = (const float*)d_in[21];
    const float* n2_w = (const float*)d_in[22];
    const float* oln_w = (const float*)d_in[23];

    char* ws = (char*)d_ws;
    const size_t MB2 = 2097152;       // 1M bf16
    const size_t ACT_BF = 8388608;    // 4M bf16
    const size_t ACT_F32 = 16777216;  // 4M f32
    unsigned short* Wbf[7];
    for (int i = 0; i < 7; ++i) Wbf[i] = (unsigned short*)(ws + i * MB2);
    size_t off = 7 * MB2;
    unsigned short* Xbf = (unsigned short*)(ws + off); off += ACT_BF;
    unsigned short* Ebf = (unsigned short*)(ws + off); off += ACT_BF;
    unsigned short* Abf = (unsigned short*)(ws + off); off += ACT_BF;
    unsigned short* Cbf = (unsigned short*)(ws + off); off += ACT_BF;
    unsigned short* Qbf = (unsigned short*)(ws + off); off += ACT_BF;
    unsigned short* Kbf = (unsigned short*)(ws + off); off += ACT_BF;
    unsigned short* Vbf = (unsigned short*)(ws + off); off += ACT_BF;
    unsigned short* Vtb = (unsigned short*)(ws + off); off += ACT_BF;
    float* ctx = (float*)(ws + off); off += ACT_F32;   // also reused as h
    float* a_f32 = (float*)(ws + off); off += ACT_F32;
    float* c_f32 = (float*)(ws + off); off += ACT_F32;
    float* h_f32 = ctx;
    float* outp = (float*)d_out;

    dim3 blk(256);
    dim3 gemm_grid(32, 8);      // 4096/128 x 1024/128
    dim3 attn_grid(16, 16, 4);  // q-tiles x H x N
    const int M = 4096, D = 1024, K = 1024;

    // converts
    k_f32_to_bf16<<<dim3(2048), blk, 0, stream>>>(dec, Xbf, 524288);
    k_f32_to_bf16<<<dim3(2048), blk, 0, stream>>>(enc, Ebf, 524288);
    for (int i = 0; i < 7; ++i)
        k_f32_to_bf16<<<dim3(512), blk, 0, stream>>>(Wsrc[i], Wbf[i], 131072);

    // ---- self attention ----
    k_gemm_bias<<<gemm_grid, blk, 0, stream>>>(Xbf, Wbf[0], b_saq, Qbf, M, D, K, 0);
    k_gemm_bias<<<gemm_grid, blk, 0, stream>>>(Xbf, Wbf[1], b_sak, Kbf, M, D, K, 0);
    k_gemm_bias<<<gemm_grid, blk, 0, stream>>>(Xbf, Wbf[2], b_sav, Vbf, M, D, K, 0);
    k_transpose_v<<<attn_grid, blk, 0, stream>>>(Vbf, Vtb);
    k_flash_attn<<<attn_grid, blk, 0, stream>>>(Qbf, Kbf, Vtb, dec_mask, ctx, 1);
    k_add_ln<<<dim3(4096), blk, 0, stream>>>(ctx, dec, n1_w, n1_b, a_f32, Abf);

    // ---- cross attention ----
    k_gemm_bias<<<gemm_grid, blk, 0, stream>>>(Abf, Wbf[3], b_caq, Qbf, M, D, K, 0);
    k_gemm_bias<<<gemm_grid, blk, 0, stream>>>(Ebf, Wbf[4], b_cak, Kbf, M, D, K, 0);
    k_gemm_bias<<<gemm_grid, blk, 0, stream>>>(Ebf, Wbf[5], b_cav, Vbf, M, D, K, 0);
    k_transpose_v<<<attn_grid, blk, 0, stream>>>(Vbf, Vtb);
    k_flash_attn<<<attn_grid, blk, 0, stream>>>(Qbf, Kbf, Vtb, enc_mask, ctx, 0);
    k_add_ln<<<dim3(4096), blk, 0, stream>>>(a_f32, ctx, n2_w, n2_b, c_f32, Cbf);

    // ---- output dense + final LN ----
    k_gemm_bias<<<gemm_grid, blk, 0, stream>>>(Cbf, Wbf[6], b_out, h_f32, M, D, K, 1);
    k_add_ln<<<dim3(4096), blk, 0, stream>>>(h_f32, c_f32, oln_w, oln_b, outp, (unsigned short*)nullptr);
}

// Round 2
// 509.572 us; speedup vs baseline: 1.1393x; 1.1393x over previous
//
#include <hip/hip_runtime.h>
#include <cstdint>
#include <cstddef>

// ---------------- types ----------------
typedef __bf16 bf16x8 __attribute__((ext_vector_type(8)));
typedef float  floatx4 __attribute__((ext_vector_type(4)));
typedef unsigned short ushortx8 __attribute__((ext_vector_type(8)));
typedef unsigned short ushortx4 __attribute__((ext_vector_type(4)));

#define MFMA16(a, b, c) __builtin_amdgcn_mfma_f32_16x16x32_bf16((a), (b), (c), 0, 0, 0)

__device__ inline unsigned short f2bf(float f) {
    unsigned int u = __float_as_uint(f);
    unsigned int r = (u + 0x7fffu + ((u >> 16) & 1u)) >> 16;
    return (unsigned short)r;
}

// ---------------- fp32 -> bf16 convert ----------------
__global__ __launch_bounds__(256) void k_f32_to_bf16(const float* __restrict__ src,
                                                     unsigned short* __restrict__ dst,
                                                     int n8) {
    int i = blockIdx.x * 256 + threadIdx.x;
    if (i >= n8) return;
    const float4* s = (const float4*)src + (size_t)i * 2;
    float4 x0 = s[0], x1 = s[1];
    ushortx8 o;
    o[0] = f2bf(x0.x); o[1] = f2bf(x0.y); o[2] = f2bf(x0.z); o[3] = f2bf(x0.w);
    o[4] = f2bf(x1.x); o[5] = f2bf(x1.y); o[6] = f2bf(x1.z); o[7] = f2bf(x1.w);
    *((ushortx8*)dst + i) = o;
}

// ---------------- GEMM: C[M][Nc] = A[M][K] @ W[Nc][K]^T + bias ----------------
// MODE 0: fused QKV (cols 0-1023 Q-pack, 1024-2047 K-pack, 2048-3071 V-tiled)
// MODE 1: Q-pack only
// MODE 2: fused KV (cols 0-1023 K-pack, 1024-2047 V-tiled)
// MODE 3: f32 row-major
// Pack layouts: Q/K[b][h][l][64] bf16; V[b][h][l/32][d(64)][l%32] bf16.
template <int MODE>
__global__ __launch_bounds__(256) void k_gemm_bias(const unsigned short* __restrict__ A,
                                                   const unsigned short* __restrict__ W,
                                                   const float* __restrict__ bias0,
                                                   const float* __restrict__ bias1,
                                                   const float* __restrict__ bias2,
                                                   void* __restrict__ d0,
                                                   void* __restrict__ d1,
                                                   void* __restrict__ d2,
                                                   int K) {
    __shared__ __align__(16) unsigned short As[128 * 32];
    __shared__ __align__(16) unsigned short Bs[128 * 32];
    const int tid = threadIdx.x;
    const int wave = tid >> 6, lane = tid & 63;
    const int quad = lane >> 4, l15 = lane & 15;
    const int wm = wave >> 1, wn = wave & 1;
    const int m0 = blockIdx.x * 128, n0 = blockIdx.y * 128;

    const size_t rowbytes = (size_t)K * 2;
    const int idx0 = tid, idx1 = 256 + tid;
    const int rA0 = idx0 >> 2, cb0 = (idx0 & 3) << 4;
    const int rA1 = idx1 >> 2, cb1 = (idx1 & 3) << 4;
    const char* gA0 = (const char*)A + (size_t)(m0 + rA0) * rowbytes + cb0;
    const char* gA1 = (const char*)A + (size_t)(m0 + rA1) * rowbytes + cb1;
    const char* gB0 = (const char*)W + (size_t)(n0 + rA0) * rowbytes + cb0;
    const char* gB1 = (const char*)W + (size_t)(n0 + rA1) * rowbytes + cb1;

    int4 pa0 = *(const int4*)gA0, pa1 = *(const int4*)gA1;
    int4 pb0 = *(const int4*)gB0, pb1 = *(const int4*)gB1;

    floatx4 acc[4][4] = {};

    const int KT = K >> 5;
    for (int kt = 0; kt < KT; ++kt) {
        __syncthreads();
        ((int4*)As)[idx0] = pa0; ((int4*)As)[idx1] = pa1;
        ((int4*)Bs)[idx0] = pb0; ((int4*)Bs)[idx1] = pb1;
        __syncthreads();
        if (kt + 1 < KT) {
            gA0 += 64; gA1 += 64; gB0 += 64; gB1 += 64;
            pa0 = *(const int4*)gA0; pa1 = *(const int4*)gA1;
            pb0 = *(const int4*)gB0; pb1 = *(const int4*)gB1;
        }
        bf16x8 af[4], bfr[4];
        const char* Asb = (const char*)As;
        const char* Bsb = (const char*)Bs;
#pragma unroll
        for (int r = 0; r < 4; ++r)
            af[r] = *(const bf16x8*)(Asb + ((wm * 64 + r * 16 + l15) * 64 + quad * 16));
#pragma unroll
        for (int c = 0; c < 4; ++c)
            bfr[c] = *(const bf16x8*)(Bsb + ((wn * 64 + c * 16 + l15) * 64 + quad * 16));
#pragma unroll
        for (int r = 0; r < 4; ++r)
#pragma unroll
            for (int c = 0; c < 4; ++c)
                acc[r][c] = MFMA16(af[r], bfr[c], acc[r][c]);
    }

    // epilogue: C row = quad*4+i (within 16-row frag), col = l15
#pragma unroll
    for (int c = 0; c < 4; ++c) {
        int col = n0 + wn * 64 + c * 16 + l15;
        int sect = col >> 10, cc = col & 1023;
        float bv;
        if (MODE == 3) bv = bias0[col];
        else if (MODE == 0) bv = (sect == 0 ? bias0 : (sect == 1 ? bias1 : bias2))[cc];
        else if (MODE == 2) bv = (sect == 0 ? bias0 : bias1)[cc];
        else bv = bias0[cc];
        int h = cc >> 6, d = cc & 63;
#pragma unroll
        for (int r = 0; r < 4; ++r) {
            int mrow = m0 + wm * 64 + r * 16 + quad * 4;
#pragma unroll
            for (int i = 0; i < 4; ++i) {
                float v = acc[r][c][i] + bv;
                int row = mrow + i;
                if (MODE == 3) {
                    ((float*)d0)[(size_t)row * 1024 + col] = v;
                } else {
                    int b = row >> 10, l = row & 1023;
                    unsigned short* base;
                    bool isV;
                    if (MODE == 0) { base = (unsigned short*)(sect == 0 ? d0 : (sect == 1 ? d1 : d2)); isV = (sect == 2); }
                    else if (MODE == 2) { base = (unsigned short*)(sect == 0 ? d0 : d1); isV = (sect == 1); }
                    else { base = (unsigned short*)d0; isV = false; }
                    size_t off;
                    if (isV) off = (size_t)(b * 16 + h) * 65536 + (size_t)(l >> 5) * 2048 + d * 32 + (l & 31);
                    else off = ((size_t)(b * 16 + h) * 1024 + l) * 64 + d;
                    base[off] = f2bf(v);
                }
            }
        }
    }
}

// ---------------- flash attention (barrier-free, packed layouts) ----------------
// Qp,Kp: [b][h][1024][64] bf16; Vp: [b][h][32][64][32] bf16 (k-tiled V^T);
// mask: [b][1024] float. Block: (q-tile of 64, h, b); each wave owns 16 q rows.
__global__ __launch_bounds__(256) void k_flash_attn(const unsigned short* __restrict__ Qp,
                                                    const unsigned short* __restrict__ Kp,
                                                    const unsigned short* __restrict__ Vp,
                                                    const float* __restrict__ mask,
                                                    float* __restrict__ ctx,
                                                    int causal) {
    const int L = 1024, D = 1024;
    int qi = blockIdx.x, h = blockIdx.y, b = blockIdx.z;
    int tid = threadIdx.x;
    int wave = tid >> 6, lane = tid & 63, quad = lane >> 4, l15 = lane & 15;
    int qbase = qi * 64 + wave * 16;

    __shared__ __align__(16) unsigned short Plds[4][640];  // stride 40 shorts/row

    const unsigned short* Qh = Qp + ((size_t)(b * 16 + h) * 1024 + qbase) * 64;
    bf16x8 qf0 = *(const bf16x8*)(Qh + l15 * 64 + quad * 8);
    bf16x8 qf1 = *(const bf16x8*)(Qh + l15 * 64 + 32 + quad * 8);

    const unsigned short* Kh = Kp + (size_t)(b * 16 + h) * 65536;
    const unsigned short* Vh = Vp + (size_t)(b * 16 + h) * 65536;
    const float* mk = mask + b * L;

    // per-wave causal bound: this wave's rows end at qbase+15
    int ktiles = causal ? ((qbase + 16 + 31) >> 5) : (L / 32);

    floatx4 O[4] = {};
    float mrun[4] = {-1e30f, -1e30f, -1e30f, -1e30f};
    float lrun[4] = {0.f, 0.f, 0.f, 0.f};

    // prefetch tile 0
    bf16x8 kc0, kc1, kc2, kc3, vc0, vc1, vc2, vc3;
    {
        const unsigned short* kp0 = Kh + (size_t)l15 * 64;
        kc0 = *(const bf16x8*)(kp0 + quad * 8);
        kc1 = *(const bf16x8*)(kp0 + 32 + quad * 8);
        const unsigned short* kp1 = Kh + (size_t)(16 + l15) * 64;
        kc2 = *(const bf16x8*)(kp1 + quad * 8);
        kc3 = *(const bf16x8*)(kp1 + 32 + quad * 8);
        vc0 = *(const bf16x8*)(Vh + (0 * 16 + l15) * 32 + quad * 8);
        vc1 = *(const bf16x8*)(Vh + (1 * 16 + l15) * 32 + quad * 8);
        vc2 = *(const bf16x8*)(Vh + (2 * 16 + l15) * 32 + quad * 8);
        vc3 = *(const bf16x8*)(Vh + (3 * 16 + l15) * 32 + quad * 8);
    }

    for (int kt = 0; kt < ktiles; ++kt) {
        int k0 = kt * 32;
        floatx4 S0 = {}, S1 = {};
        S0 = MFMA16(qf0, kc0, S0);
        S0 = MFMA16(qf1, kc1, S0);
        S1 = MFMA16(qf0, kc2, S1);
        S1 = MFMA16(qf1, kc3, S1);

        // prefetch next tile (overlaps with softmax below)
        bf16x8 kn0 = kc0, kn1 = kc1, kn2 = kc2, kn3 = kc3;
        bf16x8 vn0 = vc0, vn1 = vc1, vn2 = vc2, vn3 = vc3;
        if (kt + 1 < ktiles) {
            int k1 = k0 + 32;
            const unsigned short* kp0 = Kh + (size_t)(k1 + l15) * 64;
            kn0 = *(const bf16x8*)(kp0 + quad * 8);
            kn1 = *(const bf16x8*)(kp0 + 32 + quad * 8);
            const unsigned short* kp1 = Kh + (size_t)(k1 + 16 + l15) * 64;
            kn2 = *(const bf16x8*)(kp1 + quad * 8);
            kn3 = *(const bf16x8*)(kp1 + 32 + quad * 8);
            const unsigned short* vp = Vh + (size_t)(kt + 1) * 2048;
            vn0 = *(const bf16x8*)(vp + (0 * 16 + l15) * 32 + quad * 8);
            vn1 = *(const bf16x8*)(vp + (1 * 16 + l15) * 32 + quad * 8);
            vn2 = *(const bf16x8*)(vp + (2 * 16 + l15) * 32 + quad * 8);
            vn3 = *(const bf16x8*)(vp + (3 * 16 + l15) * 32 + quad * 8);
        }

        // mask + scale
        float m0v = mk[k0 + l15];
        float m1v = mk[k0 + 16 + l15];
        float pen0 = (1.0f - m0v) * -10000.0f;
        float pen1 = (1.0f - m1v) * -10000.0f;
        float sv0[4], sv1[4];
#pragma unroll
        for (int i = 0; i < 4; ++i) {
            int q = qbase + quad * 4 + i;
            float a0 = S0[i] * 0.125f, a1 = S1[i] * 0.125f;
            if (causal) {
                a0 += ((k0 + l15) <= q) ? pen0 : -10000.0f;
                a1 += ((k0 + 16 + l15) <= q) ? pen1 : -10000.0f;
            } else {
                a0 += pen0;
                a1 += pen1;
            }
            sv0[i] = a0;
            sv1[i] = a1;
        }
        // online softmax (16-lane butterfly)
#pragma unroll
        for (int i = 0; i < 4; ++i) {
            float t = fmaxf(sv0[i], sv1[i]);
            t = fmaxf(t, __shfl_xor(t, 1));
            t = fmaxf(t, __shfl_xor(t, 2));
            t = fmaxf(t, __shfl_xor(t, 4));
            t = fmaxf(t, __shfl_xor(t, 8));
            float mnew = fmaxf(mrun[i], t);
            float alpha = __expf(mrun[i] - mnew);
            mrun[i] = mnew;
            float p0 = __expf(sv0[i] - mnew);
            float p1 = __expf(sv1[i] - mnew);
            float rs = p0 + p1;
            rs += __shfl_xor(rs, 1);
            rs += __shfl_xor(rs, 2);
            rs += __shfl_xor(rs, 4);
            rs += __shfl_xor(rs, 8);
            lrun[i] = lrun[i] * alpha + rs;
#pragma unroll
            for (int f = 0; f < 4; ++f) O[f][i] *= alpha;
            sv0[i] = p0;
            sv1[i] = p1;
        }
        // P: C-layout -> A-layout via per-wave LDS round trip (NO barrier: wave-private)
        unsigned short* pw = &Plds[wave][0];
#pragma unroll
        for (int i = 0; i < 4; ++i) {
            pw[(quad * 4 + i) * 40 + l15] = f2bf(sv0[i]);
            pw[(quad * 4 + i) * 40 + 16 + l15] = f2bf(sv1[i]);
        }
        bf16x8 pa = *(const bf16x8*)(pw + l15 * 40 + quad * 8);
        O[0] = MFMA16(pa, vc0, O[0]);
        O[1] = MFMA16(pa, vc1, O[1]);
        O[2] = MFMA16(pa, vc2, O[2]);
        O[3] = MFMA16(pa, vc3, O[3]);

        kc0 = kn0; kc1 = kn1; kc2 = kn2; kc3 = kn3;
        vc0 = vn0; vc1 = vn1; vc2 = vn2; vc3 = vn3;
    }
    // epilogue: ctx = O / l   (row-major [b][l][h*64+d])
#pragma unroll
    for (int i = 0; i < 4; ++i) {
        float inv = 1.0f / lrun[i];
        int q = qbase + quad * 4 + i;
        float* op = ctx + ((size_t)(b * L + q)) * D + h * 64;
#pragma unroll
        for (int f = 0; f < 4; ++f) op[f * 16 + l15] = O[f][i] * inv;
    }
}

// ---------------- add + layernorm (one block per 1024-row) ----------------
__global__ __launch_bounds__(256) void k_add_ln(const float* __restrict__ X,
                                                const float* __restrict__ Y,
                                                const float* __restrict__ w,
                                                const float* __restrict__ bvec,
                                                float* __restrict__ outf,
                                                unsigned short* __restrict__ outbf) {
    int row = blockIdx.x;
    int tid = threadIdx.x;
    float4 x = *((const float4*)(X + (size_t)row * 1024) + tid);
    float4 y = *((const float4*)(Y + (size_t)row * 1024) + tid);
    float v0 = x.x + y.x, v1 = x.y + y.y, v2 = x.z + y.z, v3 = x.w + y.w;
    float s = v0 + v1 + v2 + v3;
    float s2 = v0 * v0 + v1 * v1 + v2 * v2 + v3 * v3;
#pragma unroll
    for (int off = 32; off > 0; off >>= 1) {
        s += __shfl_xor(s, off);
        s2 += __shfl_xor(s2, off);
    }
    __shared__ float red[8];
    int wave = tid >> 6, lane = tid & 63;
    if (lane == 0) { red[wave] = s; red[4 + wave] = s2; }
    __syncthreads();
    s = red[0] + red[1] + red[2] + red[3];
    s2 = red[4] + red[5] + red[6] + red[7];
    float u = s * (1.0f / 1024.0f);
    float var = s2 * (1.0f / 1024.0f) - u * u;
    float r = 1.0f / sqrtf(fmaxf(var, 0.0f) + 1e-12f);
    float4 wv = *((const float4*)w + tid);
    float4 bv = *((const float4*)bvec + tid);
    float o0 = wv.x * (v0 - u) * r + bv.x;
    float o1 = wv.y * (v1 - u) * r + bv.y;
    float o2 = wv.z * (v2 - u) * r + bv.z;
    float o3 = wv.w * (v3 - u) * r + bv.w;
    float4 o = {o0, o1, o2, o3};
    *((float4*)(outf + (size_t)row * 1024) + tid) = o;
    if (outbf) {
        ushortx4 ob;
        ob[0] = f2bf(o0); ob[1] = f2bf(o1); ob[2] = f2bf(o2); ob[3] = f2bf(o3);
        *((ushortx4*)outbf + (size_t)row * 256 + tid) = ob;
    }
}

// ---------------- host ----------------
extern "C" void kernel_launch(void* const* d_in, const int* in_sizes, int n_in,
                              void* d_out, int out_size, void* d_ws, size_t ws_size,
                              hipStream_t stream) {
    (void)in_sizes; (void)n_in; (void)out_size; (void)ws_size;
    const float* dec = (const float*)d_in[0];
    const float* enc = (const float*)d_in[1];
    const float* dec_mask = (const float*)d_in[2];
    const float* enc_mask = (const float*)d_in[3];
    const float* Wsrc[7];
    for (int i = 0; i < 7; ++i) Wsrc[i] = (const float*)d_in[4 + i];
    const float* b_saq = (const float*)d_in[11];
    const float* b_sak = (const float*)d_in[12];
    const float* b_sav = (const float*)d_in[13];
    const float* b_caq = (const float*)d_in[14];
    const float* b_cak = (const float*)d_in[15];
    const float* b_cav = (const float*)d_in[16];
    const float* b_out = (const float*)d_in[17];
    const float* n1_b = (const float*)d_in[18];
    const float* n2_b = (const float*)d_in[19];
    const float* oln_b = (const float*)d_in[20];
    const float* n1_w = (const float*)d_in[21];
    const float* n2_w = (const float*)d_in[22];
    const float* oln_w = (const float*)d_in[23];

    char* ws = (char*)d_ws;
    const size_t MB2 = 2097152;       // 1M bf16
    const size_t ACT_BF = 8388608;    // 4M bf16
    const size_t ACT_F32 = 16777216;  // 4M f32
    unsigned short* Wbf[7];
    for (int i = 0; i < 7; ++i) Wbf[i] = (unsigned short*)(ws + i * MB2);
    size_t off = 7 * MB2;
    unsigned short* Xbf = (unsigned short*)(ws + off); off += ACT_BF;
    unsigned short* Ebf = (unsigned short*)(ws + off); off += ACT_BF;
    unsigned short* Abf = (unsigned short*)(ws + off); off += ACT_BF;
    unsigned short* Cbf = (unsigned short*)(ws + off); off += ACT_BF;
    unsigned short* Qp = (unsigned short*)(ws + off); off += ACT_BF;
    unsigned short* Kp = (unsigned short*)(ws + off); off += ACT_BF;
    unsigned short* Vp = (unsigned short*)(ws + off); off += ACT_BF;
    float* ctx = (float*)(ws + off); off += ACT_F32;   // reused as h
    float* a_f32 = (float*)(ws + off); off += ACT_F32;
    float* c_f32 = (float*)(ws + off); off += ACT_F32;
    float* h_f32 = ctx;
    float* outp = (float*)d_out;

    dim3 blk(256);
    dim3 attn_grid(16, 16, 4);

    // converts (Wbf[0..2] and Wbf[4..5] are contiguous for fused GEMMs)
    k_f32_to_bf16<<<dim3(2048), blk, 0, stream>>>(dec, Xbf, 524288);
    k_f32_to_bf16<<<dim3(2048), blk, 0, stream>>>(enc, Ebf, 524288);
    for (int i = 0; i < 7; ++i)
        k_f32_to_bf16<<<dim3(512), blk, 0, stream>>>(Wsrc[i], Wbf[i], 131072);

    // ---- self attention: fused QKV GEMM (N=3072) ----
    k_gemm_bias<0><<<dim3(32, 24), blk, 0, stream>>>(Xbf, Wbf[0], b_saq, b_sak, b_sav,
                                                     Qp, Kp, Vp, 1024);
    k_flash_attn<<<attn_grid, blk, 0, stream>>>(Qp, Kp, Vp, dec_mask, ctx, 1);
    k_add_ln<<<dim3(4096), blk, 0, stream>>>(ctx, dec, n1_w, n1_b, a_f32, Abf);

    // ---- cross attention: Q GEMM + fused KV GEMM (N=2048) ----
    k_gemm_bias<1><<<dim3(32, 8), blk, 0, stream>>>(Abf, Wbf[3], b_caq, nullptr, nullptr,
                                                    Qp, nullptr, nullptr, 1024);
    k_gemm_bias<2><<<dim3(32, 16), blk, 0, stream>>>(Ebf, Wbf[4], b_cak, b_cav, nullptr,
                                                     Kp, Vp, nullptr, 1024);
    k_flash_attn<<<attn_grid, blk, 0, stream>>>(Qp, Kp, Vp, enc_mask, ctx, 0);
    k_add_ln<<<dim3(4096), blk, 0, stream>>>(a_f32, ctx, n2_w, n2_b, c_f32, Cbf);

    // ---- output dense + final LN ----
    k_gemm_bias<3><<<dim3(32, 8), blk, 0, stream>>>(Cbf, Wbf[6], b_out, nullptr, nullptr,
                                                    h_f32, nullptr, nullptr, 1024);
    k_add_ln<<<dim3(4096), blk, 0, stream>>>(h_f32, c_f32, oln_w, oln_b, outp, (unsigned short*)nullptr);
}

// Round 3
// 454.493 us; speedup vs baseline: 1.2774x; 1.1212x over previous
//
#include <hip/hip_runtime.h>
#include <cstdint>
#include <cstddef>

// ---------------- types ----------------
typedef __bf16 bf16x8 __attribute__((ext_vector_type(8)));
typedef float  floatx4 __attribute__((ext_vector_type(4)));
typedef unsigned short ushortx8 __attribute__((ext_vector_type(8)));
typedef unsigned short ushortx4 __attribute__((ext_vector_type(4)));

#define MFMA16(a, b, c) __builtin_amdgcn_mfma_f32_16x16x32_bf16((a), (b), (c), 0, 0, 0)

__device__ inline unsigned short f2bf(float f) {
    unsigned int u = __float_as_uint(f);
    unsigned int r = (u + 0x7fffu + ((u >> 16) & 1u)) >> 16;
    return (unsigned short)r;
}

// ---------------- fp32 -> bf16 convert ----------------
__global__ __launch_bounds__(256) void k_f32_to_bf16(const float* __restrict__ src,
                                                     unsigned short* __restrict__ dst,
                                                     int n8) {
    int i = blockIdx.x * 256 + threadIdx.x;
    if (i >= n8) return;
    const float4* s = (const float4*)src + (size_t)i * 2;
    float4 x0 = s[0], x1 = s[1];
    ushortx8 o;
    o[0] = f2bf(x0.x); o[1] = f2bf(x0.y); o[2] = f2bf(x0.z); o[3] = f2bf(x0.w);
    o[4] = f2bf(x1.x); o[5] = f2bf(x1.y); o[6] = f2bf(x1.z); o[7] = f2bf(x1.w);
    *((ushortx8*)dst + i) = o;
}

// ---------------- GEMM: C[M][Nc] = A[M][K] @ W[Nc][K]^T + bias ----------------
// MODE 0: fused QKV (cols 0-1023 Q-pack, 1024-2047 K-pack, 2048-3071 V-tiled)
// MODE 1: Q-pack only
// MODE 2: fused KV (cols 0-1023 K-pack, 1024-2047 V-tiled)
// MODE 3: f32 row-major
// Pack layouts: Q/K[b][h][l][64] bf16; V[b][h][l/32][d(64)][l%32] bf16.
template <int MODE>
__global__ __launch_bounds__(256) void k_gemm_bias(const unsigned short* __restrict__ A,
                                                   const unsigned short* __restrict__ W,
                                                   const float* __restrict__ bias0,
                                                   const float* __restrict__ bias1,
                                                   const float* __restrict__ bias2,
                                                   void* __restrict__ d0,
                                                   void* __restrict__ d1,
                                                   void* __restrict__ d2,
                                                   int K) {
    __shared__ __align__(16) unsigned short As[128 * 32];
    __shared__ __align__(16) unsigned short Bs[128 * 32];
    const int tid = threadIdx.x;
    const int wave = tid >> 6, lane = tid & 63;
    const int quad = lane >> 4, l15 = lane & 15;
    const int wm = wave >> 1, wn = wave & 1;
    const int m0 = blockIdx.x * 128, n0 = blockIdx.y * 128;

    const size_t rowbytes = (size_t)K * 2;
    const int idx0 = tid, idx1 = 256 + tid;
    const int rA0 = idx0 >> 2, cb0 = (idx0 & 3) << 4;
    const int rA1 = idx1 >> 2, cb1 = (idx1 & 3) << 4;
    const char* gA0 = (const char*)A + (size_t)(m0 + rA0) * rowbytes + cb0;
    const char* gA1 = (const char*)A + (size_t)(m0 + rA1) * rowbytes + cb1;
    const char* gB0 = (const char*)W + (size_t)(n0 + rA0) * rowbytes + cb0;
    const char* gB1 = (const char*)W + (size_t)(n0 + rA1) * rowbytes + cb1;

    int4 pa0 = *(const int4*)gA0, pa1 = *(const int4*)gA1;
    int4 pb0 = *(const int4*)gB0, pb1 = *(const int4*)gB1;

    floatx4 acc[4][4] = {};

    const int KT = K >> 5;
    for (int kt = 0; kt < KT; ++kt) {
        __syncthreads();
        ((int4*)As)[idx0] = pa0; ((int4*)As)[idx1] = pa1;
        ((int4*)Bs)[idx0] = pb0; ((int4*)Bs)[idx1] = pb1;
        __syncthreads();
        if (kt + 1 < KT) {
            gA0 += 64; gA1 += 64; gB0 += 64; gB1 += 64;
            pa0 = *(const int4*)gA0; pa1 = *(const int4*)gA1;
            pb0 = *(const int4*)gB0; pb1 = *(const int4*)gB1;
        }
        bf16x8 af[4], bfr[4];
        const char* Asb = (const char*)As;
        const char* Bsb = (const char*)Bs;
#pragma unroll
        for (int r = 0; r < 4; ++r)
            af[r] = *(const bf16x8*)(Asb + ((wm * 64 + r * 16 + l15) * 64 + quad * 16));
#pragma unroll
        for (int c = 0; c < 4; ++c)
            bfr[c] = *(const bf16x8*)(Bsb + ((wn * 64 + c * 16 + l15) * 64 + quad * 16));
#pragma unroll
        for (int r = 0; r < 4; ++r)
#pragma unroll
            for (int c = 0; c < 4; ++c)
                acc[r][c] = MFMA16(af[r], bfr[c], acc[r][c]);
    }

    // epilogue: C row = quad*4+i (within 16-row frag), col = l15
#pragma unroll
    for (int c = 0; c < 4; ++c) {
        int col = n0 + wn * 64 + c * 16 + l15;
        int sect = col >> 10, cc = col & 1023;
        float bv;
        if (MODE == 3) bv = bias0[col];
        else if (MODE == 0) bv = (sect == 0 ? bias0 : (sect == 1 ? bias1 : bias2))[cc];
        else if (MODE == 2) bv = (sect == 0 ? bias0 : bias1)[cc];
        else bv = bias0[cc];
        int h = cc >> 6, d = cc & 63;
#pragma unroll
        for (int r = 0; r < 4; ++r) {
            int mrow = m0 + wm * 64 + r * 16 + quad * 4;
#pragma unroll
            for (int i = 0; i < 4; ++i) {
                float v = acc[r][c][i] + bv;
                int row = mrow + i;
                if (MODE == 3) {
                    ((float*)d0)[(size_t)row * 1024 + col] = v;
                } else {
                    int b = row >> 10, l = row & 1023;
                    unsigned short* base;
                    bool isV;
                    if (MODE == 0) { base = (unsigned short*)(sect == 0 ? d0 : (sect == 1 ? d1 : d2)); isV = (sect == 2); }
                    else if (MODE == 2) { base = (unsigned short*)(sect == 0 ? d0 : d1); isV = (sect == 1); }
                    else { base = (unsigned short*)d0; isV = false; }
                    size_t off;
                    if (isV) off = (size_t)(b * 16 + h) * 65536 + (size_t)(l >> 5) * 2048 + d * 32 + (l & 31);
                    else off = ((size_t)(b * 16 + h) * 1024 + l) * 64 + d;
                    base[off] = f2bf(v);
                }
            }
        }
    }
}

// ---------------- flash attention v3 ----------------
// Qp,Kp: [b][h][1024][64] bf16; Vp: [b][h][32][64][32] bf16; mask: [b][1024] f32.
// Flat grid 1024, XCD-swizzled so all 16 q-tiles of one (b,h) share an XCD.
// Wave = 16 q rows; k-tile = 64; no running max (scores bounded; masked -> exp->0);
// l-reduction deferred to the end => zero per-tile shuffles, zero in-loop barriers.
__global__ __launch_bounds__(256) void k_flash_attn(const unsigned short* __restrict__ Qp,
                                                    const unsigned short* __restrict__ Kp,
                                                    const unsigned short* __restrict__ Vp,
                                                    const float* __restrict__ mask,
                                                    float* __restrict__ ctx,
                                                    int causal) {
    const int L = 1024, D = 1024;
    int f = blockIdx.x;
    int low3 = f & 7, qi = (f >> 3) & 15, g = f >> 7;
    int bh = g * 8 + low3;           // 0..63; constant (mod 8) per (b,h) group
    int h = bh & 15, b = bh >> 4;

    int tid = threadIdx.x;
    int wave = tid >> 6, lane = tid & 63, quad = lane >> 4, l15 = lane & 15;
    int qbase = qi * 64 + wave * 16;

    __shared__ float penLDS[1024];                       // 4 KB
    __shared__ __align__(16) unsigned short Plds[4][1280];  // per-wave Plo[16][40], Phi[16][40]

    // stage mask penalty once per block
    {
        float4 mv = ((const float4*)(mask + b * L))[tid];
        float4 pv;
        pv.x = (1.0f - mv.x) * -10000.0f;
        pv.y = (1.0f - mv.y) * -10000.0f;
        pv.z = (1.0f - mv.z) * -10000.0f;
        pv.w = (1.0f - mv.w) * -10000.0f;
        ((float4*)penLDS)[tid] = pv;
    }
    __syncthreads();

    const unsigned short* Qh = Qp + ((size_t)(b * 16 + h) * 1024 + qbase) * 64;
    bf16x8 qf0 = *(const bf16x8*)(Qh + l15 * 64 + quad * 8);
    bf16x8 qf1 = *(const bf16x8*)(Qh + l15 * 64 + 32 + quad * 8);

    const unsigned short* Kh = Kp + (size_t)(b * 16 + h) * 65536;
    const unsigned short* Vh = Vp + (size_t)(b * 16 + h) * 65536;

    int ktiles = causal ? ((qbase + 16 + 63) >> 6) : (L / 64);

    floatx4 O[4] = {};
    float lsum[4] = {0.f, 0.f, 0.f, 0.f};

    unsigned short* pw_lo = &Plds[wave][0];
    unsigned short* pw_hi = &Plds[wave][640];

    // K fragments for tile 0
    bf16x8 kc[8];
#pragma unroll
    for (int r = 0; r < 4; ++r) {
        const unsigned short* kp = Kh + (size_t)(r * 16 + l15) * 64;
        kc[2 * r] = *(const bf16x8*)(kp + quad * 8);
        kc[2 * r + 1] = *(const bf16x8*)(kp + 32 + quad * 8);
    }

    for (int kt = 0; kt < ktiles; ++kt) {
        int k0 = kt * 64;
        // V loads for THIS tile (consumed after softmax — long slack)
        bf16x8 vv[8];
#pragma unroll
        for (int s = 0; s < 2; ++s)
#pragma unroll
            for (int fi = 0; fi < 4; ++fi)
                vv[s * 4 + fi] = *(const bf16x8*)(Vh + (size_t)(2 * kt + s) * 2048 +
                                                  (fi * 16 + l15) * 32 + quad * 8);
        // penalties from LDS
        float pen0 = penLDS[k0 + l15];
        float pen1 = penLDS[k0 + 16 + l15];
        float pen2v = penLDS[k0 + 32 + l15];
        float pen3 = penLDS[k0 + 48 + l15];

        // S = Q @ K^T  (16 q x 64 k)
        floatx4 S0 = {}, S1 = {}, S2 = {}, S3 = {};
        S0 = MFMA16(qf0, kc[0], S0); S0 = MFMA16(qf1, kc[1], S0);
        S1 = MFMA16(qf0, kc[2], S1); S1 = MFMA16(qf1, kc[3], S1);
        S2 = MFMA16(qf0, kc[4], S2); S2 = MFMA16(qf1, kc[5], S2);
        S3 = MFMA16(qf0, kc[6], S3); S3 = MFMA16(qf1, kc[7], S3);

        // K prefetch for next tile (consumed at next loop top)
        if (kt + 1 < ktiles) {
            int k1 = k0 + 64;
#pragma unroll
            for (int r = 0; r < 4; ++r) {
                const unsigned short* kp = Kh + (size_t)(k1 + r * 16 + l15) * 64;
                kc[2 * r] = *(const bf16x8*)(kp + quad * 8);
                kc[2 * r + 1] = *(const bf16x8*)(kp + 32 + quad * 8);
            }
        }

        // softmax numerator (no max subtraction): p = exp(S/8 + pen); masked -> 0
#pragma unroll
        for (int i = 0; i < 4; ++i) {
            float e0, e1, e2, e3;
            if (causal) {
                int q = qbase + quad * 4 + i;
                e0 = ((k0 + l15) <= q) ? pen0 : -10000.0f;
                e1 = ((k0 + 16 + l15) <= q) ? pen1 : -10000.0f;
                e2 = ((k0 + 32 + l15) <= q) ? pen2v : -10000.0f;
                e3 = ((k0 + 48 + l15) <= q) ? pen3 : -10000.0f;
            } else {
                e0 = pen0; e1 = pen1; e2 = pen2v; e3 = pen3;
            }
            float p0 = __expf(fmaf(S0[i], 0.125f, e0));
            float p1 = __expf(fmaf(S1[i], 0.125f, e1));
            float p2 = __expf(fmaf(S2[i], 0.125f, e2));
            float p3 = __expf(fmaf(S3[i], 0.125f, e3));
            lsum[i] += (p0 + p1) + (p2 + p3);
            int ro = (quad * 4 + i) * 40;
            pw_lo[ro + l15] = f2bf(p0);
            pw_lo[ro + 16 + l15] = f2bf(p1);
            pw_hi[ro + l15] = f2bf(p2);
            pw_hi[ro + 16 + l15] = f2bf(p3);
        }
        // P (A-layout) and PV
        bf16x8 pa_lo = *(const bf16x8*)(pw_lo + l15 * 40 + quad * 8);
        bf16x8 pa_hi = *(const bf16x8*)(pw_hi + l15 * 40 + quad * 8);
        O[0] = MFMA16(pa_lo, vv[0], O[0]);
        O[1] = MFMA16(pa_lo, vv[1], O[1]);
        O[2] = MFMA16(pa_lo, vv[2], O[2]);
        O[3] = MFMA16(pa_lo, vv[3], O[3]);
        O[0] = MFMA16(pa_hi, vv[4], O[0]);
        O[1] = MFMA16(pa_hi, vv[5], O[1]);
        O[2] = MFMA16(pa_hi, vv[6], O[2]);
        O[3] = MFMA16(pa_hi, vv[7], O[3]);
    }

    // final l-reduction (once, not per tile) + write
#pragma unroll
    for (int i = 0; i < 4; ++i) {
        float l = lsum[i];
        l += __shfl_xor(l, 1);
        l += __shfl_xor(l, 2);
        l += __shfl_xor(l, 4);
        l += __shfl_xor(l, 8);
        float inv = 1.0f / l;
        int q = qbase + quad * 4 + i;
        float* op = ctx + ((size_t)(b * L + q)) * D + h * 64;
#pragma unroll
        for (int fi = 0; fi < 4; ++fi) op[fi * 16 + l15] = O[fi][i] * inv;
    }
}

// ---------------- add + layernorm (one block per 1024-row) ----------------
__global__ __launch_bounds__(256) void k_add_ln(const float* __restrict__ X,
                                                const float* __restrict__ Y,
                                                const float* __restrict__ w,
                                                const float* __restrict__ bvec,
                                                float* __restrict__ outf,
                                                unsigned short* __restrict__ outbf) {
    int row = blockIdx.x;
    int tid = threadIdx.x;
    float4 x = *((const float4*)(X + (size_t)row * 1024) + tid);
    float4 y = *((const float4*)(Y + (size_t)row * 1024) + tid);
    float v0 = x.x + y.x, v1 = x.y + y.y, v2 = x.z + y.z, v3 = x.w + y.w;
    float s = v0 + v1 + v2 + v3;
    float s2 = v0 * v0 + v1 * v1 + v2 * v2 + v3 * v3;
#pragma unroll
    for (int off = 32; off > 0; off >>= 1) {
        s += __shfl_xor(s, off);
        s2 += __shfl_xor(s2, off);
    }
    __shared__ float red[8];
    int wave = tid >> 6, lane = tid & 63;
    if (lane == 0) { red[wave] = s; red[4 + wave] = s2; }
    __syncthreads();
    s = red[0] + red[1] + red[2] + red[3];
    s2 = red[4] + red[5] + red[6] + red[7];
    float u = s * (1.0f / 1024.0f);
    float var = s2 * (1.0f / 1024.0f) - u * u;
    float r = 1.0f / sqrtf(fmaxf(var, 0.0f) + 1e-12f);
    float4 wv = *((const float4*)w + tid);
    float4 bv = *((const float4*)bvec + tid);
    float o0 = wv.x * (v0 - u) * r + bv.x;
    float o1 = wv.y * (v1 - u) * r + bv.y;
    float o2 = wv.z * (v2 - u) * r + bv.z;
    float o3 = wv.w * (v3 - u) * r + bv.w;
    float4 o = {o0, o1, o2, o3};
    *((float4*)(outf + (size_t)row * 1024) + tid) = o;
    if (outbf) {
        ushortx4 ob;
        ob[0] = f2bf(o0); ob[1] = f2bf(o1); ob[2] = f2bf(o2); ob[3] = f2bf(o3);
        *((ushortx4*)outbf + (size_t)row * 256 + tid) = ob;
    }
}

// ---------------- host ----------------
extern "C" void kernel_launch(void* const* d_in, const int* in_sizes, int n_in,
                              void* d_out, int out_size, void* d_ws, size_t ws_size,
                              hipStream_t stream) {
    (void)in_sizes; (void)n_in; (void)out_size; (void)ws_size;
    const float* dec = (const float*)d_in[0];
    const float* enc = (const float*)d_in[1];
    const float* dec_mask = (const float*)d_in[2];
    const float* enc_mask = (const float*)d_in[3];
    const float* Wsrc[7];
    for (int i = 0; i < 7; ++i) Wsrc[i] = (const float*)d_in[4 + i];
    const float* b_saq = (const float*)d_in[11];
    const float* b_sak = (const float*)d_in[12];
    const float* b_sav = (const float*)d_in[13];
    const float* b_caq = (const float*)d_in[14];
    const float* b_cak = (const float*)d_in[15];
    const float* b_cav = (const float*)d_in[16];
    const float* b_out = (const float*)d_in[17];
    const float* n1_b = (const float*)d_in[18];
    const float* n2_b = (const float*)d_in[19];
    const float* oln_b = (const float*)d_in[20];
    const float* n1_w = (const float*)d_in[21];
    const float* n2_w = (const float*)d_in[22];
    const float* oln_w = (const float*)d_in[23];

    char* ws = (char*)d_ws;
    const size_t MB2 = 2097152;       // 1M bf16
    const size_t ACT_BF = 8388608;    // 4M bf16
    const size_t ACT_F32 = 16777216;  // 4M f32
    unsigned short* Wbf[7];
    for (int i = 0; i < 7; ++i) Wbf[i] = (unsigned short*)(ws + i * MB2);
    size_t off = 7 * MB2;
    unsigned short* Xbf = (unsigned short*)(ws + off); off += ACT_BF;
    unsigned short* Ebf = (unsigned short*)(ws + off); off += ACT_BF;
    unsigned short* Abf = (unsigned short*)(ws + off); off += ACT_BF;
    unsigned short* Cbf = (unsigned short*)(ws + off); off += ACT_BF;
    unsigned short* Qp = (unsigned short*)(ws + off); off += ACT_BF;
    unsigned short* Kp = (unsigned short*)(ws + off); off += ACT_BF;
    unsigned short* Vp = (unsigned short*)(ws + off); off += ACT_BF;
    float* ctx = (float*)(ws + off); off += ACT_F32;   // reused as h
    float* a_f32 = (float*)(ws + off); off += ACT_F32;
    float* c_f32 = (float*)(ws + off); off += ACT_F32;
    float* h_f32 = ctx;
    float* outp = (float*)d_out;

    dim3 blk(256);
    dim3 attn_grid(1024);  // flat, XCD-swizzled in-kernel

    k_f32_to_bf16<<<dim3(2048), blk, 0, stream>>>(dec, Xbf, 524288);
    k_f32_to_bf16<<<dim3(2048), blk, 0, stream>>>(enc, Ebf, 524288);
    for (int i = 0; i < 7; ++i)
        k_f32_to_bf16<<<dim3(512), blk, 0, stream>>>(Wsrc[i], Wbf[i], 131072);

    // ---- self attention: fused QKV GEMM (N=3072) ----
    k_gemm_bias<0><<<dim3(32, 24), blk, 0, stream>>>(Xbf, Wbf[0], b_saq, b_sak, b_sav,
                                                     Qp, Kp, Vp, 1024);
    k_flash_attn<<<attn_grid, blk, 0, stream>>>(Qp, Kp, Vp, dec_mask, ctx, 1);
    k_add_ln<<<dim3(4096), blk, 0, stream>>>(ctx, dec, n1_w, n1_b, a_f32, Abf);

    // ---- cross attention: Q GEMM + fused KV GEMM (N=2048) ----
    k_gemm_bias<1><<<dim3(32, 8), blk, 0, stream>>>(Abf, Wbf[3], b_caq, nullptr, nullptr,
                                                    Qp, nullptr, nullptr, 1024);
    k_gemm_bias<2><<<dim3(32, 16), blk, 0, stream>>>(Ebf, Wbf[4], b_cak, b_cav, nullptr,
                                                     Kp, Vp, nullptr, 1024);
    k_flash_attn<<<attn_grid, blk, 0, stream>>>(Qp, Kp, Vp, enc_mask, ctx, 0);
    k_add_ln<<<dim3(4096), blk, 0, stream>>>(a_f32, ctx, n2_w, n2_b, c_f32, Cbf);

    // ---- output dense + final LN ----
    k_gemm_bias<3><<<dim3(32, 8), blk, 0, stream>>>(Cbf, Wbf[6], b_out, nullptr, nullptr,
                                                    h_f32, nullptr, nullptr, 1024);
    k_add_ln<<<dim3(4096), blk, 0, stream>>>(h_f32, c_f32, oln_w, oln_b, outp, (unsigned short*)nullptr);
}

// Round 4
// 350.954 us; speedup vs baseline: 1.6542x; 1.2950x over previous
//
#include <hip/hip_runtime.h>
#include <cstdint>
#include <cstddef>

// ---------------- types ----------------
typedef __bf16 bf16x8 __attribute__((ext_vector_type(8)));
typedef float  floatx4 __attribute__((ext_vector_type(4)));
typedef unsigned short ushortx8 __attribute__((ext_vector_type(8)));
typedef unsigned short ushortx4 __attribute__((ext_vector_type(4)));

#define MFMA16(a, b, c) __builtin_amdgcn_mfma_f32_16x16x32_bf16((a), (b), (c), 0, 0, 0)

__device__ inline unsigned short f2bf(float f) {
    unsigned int u = __float_as_uint(f);
    unsigned int r = (u + 0x7fffu + ((u >> 16) & 1u)) >> 16;
    return (unsigned short)r;
}
__device__ inline float bf2f(unsigned short u) {
    return __uint_as_float(((unsigned int)u) << 16);
}

// ---------------- converts ----------------
struct Src2 { const float* p[2]; };
__global__ __launch_bounds__(256) void k_x2_to_bf16(Src2 s2, unsigned short* __restrict__ dst) {
    int i = blockIdx.x * 256 + threadIdx.x;   // 8 elems each; 524288 per tensor
    const float* src = s2.p[i >> 19];
    int off = i & 524287;
    const float4* s = (const float4*)src + (size_t)off * 2;
    float4 x0 = s[0], x1 = s[1];
    ushortx8 o;
    o[0] = f2bf(x0.x); o[1] = f2bf(x0.y); o[2] = f2bf(x0.z); o[3] = f2bf(x0.w);
    o[4] = f2bf(x1.x); o[5] = f2bf(x1.y); o[6] = f2bf(x1.z); o[7] = f2bf(x1.w);
    *((ushortx8*)dst + i) = o;
}
struct Src7 { const float* p[7]; };
__global__ __launch_bounds__(256) void k_w7_to_bf16(Src7 s7, unsigned short* __restrict__ dst) {
    int i = blockIdx.x * 256 + threadIdx.x;   // 131072 i-units per weight
    const float* src = s7.p[i >> 17];
    int off = i & 131071;
    const float4* s = (const float4*)src + (size_t)off * 2;
    float4 x0 = s[0], x1 = s[1];
    ushortx8 o;
    o[0] = f2bf(x0.x); o[1] = f2bf(x0.y); o[2] = f2bf(x0.z); o[3] = f2bf(x0.w);
    o[4] = f2bf(x1.x); o[5] = f2bf(x1.y); o[6] = f2bf(x1.z); o[7] = f2bf(x1.w);
    *((ushortx8*)dst + i) = o;
}

// ---------------- GEMM: C[M][Nc] = A[M][K] @ W[Nc][K]^T + bias ----------------
// MODE 0: fused QKV packs (A for all sections)
// MODE 3: f32 row-major
// MODE 4: fused cross QKV (sect 0 uses A, sects 1-2 use A2)
// Pack layouts: Q/K[b][h][l][64] bf16; V[b][h][l/32][d(64)][l%32] bf16.
template <int MODE>
__global__ __launch_bounds__(256) void k_gemm_bias(const unsigned short* __restrict__ A,
                                                   const unsigned short* __restrict__ A2,
                                                   const unsigned short* __restrict__ W,
                                                   const float* __restrict__ bias0,
                                                   const float* __restrict__ bias1,
                                                   const float* __restrict__ bias2,
                                                   void* __restrict__ d0,
                                                   void* __restrict__ d1,
                                                   void* __restrict__ d2,
                                                   int K) {
    __shared__ __align__(16) unsigned short As[128 * 32];
    __shared__ __align__(16) unsigned short Bs[128 * 32];
    const int tid = threadIdx.x;
    const int wave = tid >> 6, lane = tid & 63;
    const int quad = lane >> 4, l15 = lane & 15;
    const int wm = wave >> 1, wn = wave & 1;
    const int m0 = blockIdx.x * 128, n0 = blockIdx.y * 128;
    const int sect_blk = n0 >> 10;

    const unsigned short* Ause = (MODE == 4 && sect_blk != 0) ? A2 : A;

    const size_t rowbytes = (size_t)K * 2;
    const int idx0 = tid, idx1 = 256 + tid;
    const int rA0 = idx0 >> 2, cb0 = (idx0 & 3) << 4;
    const int rA1 = idx1 >> 2, cb1 = (idx1 & 3) << 4;
    const char* gA0 = (const char*)Ause + (size_t)(m0 + rA0) * rowbytes + cb0;
    const char* gA1 = (const char*)Ause + (size_t)(m0 + rA1) * rowbytes + cb1;
    const char* gB0 = (const char*)W + (size_t)(n0 + rA0) * rowbytes + cb0;
    const char* gB1 = (const char*)W + (size_t)(n0 + rA1) * rowbytes + cb1;

    int4 pa0 = *(const int4*)gA0, pa1 = *(const int4*)gA1;
    int4 pb0 = *(const int4*)gB0, pb1 = *(const int4*)gB1;

    floatx4 acc[4][4] = {};

    const int KT = K >> 5;
    for (int kt = 0; kt < KT; ++kt) {
        __syncthreads();
        ((int4*)As)[idx0] = pa0; ((int4*)As)[idx1] = pa1;
        ((int4*)Bs)[idx0] = pb0; ((int4*)Bs)[idx1] = pb1;
        __syncthreads();
        if (kt + 1 < KT) {
            gA0 += 64; gA1 += 64; gB0 += 64; gB1 += 64;
            pa0 = *(const int4*)gA0; pa1 = *(const int4*)gA1;
            pb0 = *(const int4*)gB0; pb1 = *(const int4*)gB1;
        }
        bf16x8 af[4], bfr[4];
        const char* Asb = (const char*)As;
        const char* Bsb = (const char*)Bs;
#pragma unroll
        for (int r = 0; r < 4; ++r)
            af[r] = *(const bf16x8*)(Asb + ((wm * 64 + r * 16 + l15) * 64 + quad * 16));
#pragma unroll
        for (int c = 0; c < 4; ++c)
            bfr[c] = *(const bf16x8*)(Bsb + ((wn * 64 + c * 16 + l15) * 64 + quad * 16));
#pragma unroll
        for (int r = 0; r < 4; ++r)
#pragma unroll
            for (int c = 0; c < 4; ++c)
                acc[r][c] = MFMA16(af[r], bfr[c], acc[r][c]);
    }

    // epilogue: C row = quad*4+i, col = l15
#pragma unroll
    for (int c = 0; c < 4; ++c) {
        int col = n0 + wn * 64 + c * 16 + l15;
        int sect = col >> 10, cc = col & 1023;
        float bv;
        if (MODE == 3) bv = bias0[col];
        else bv = (sect == 0 ? bias0 : (sect == 1 ? bias1 : bias2))[cc];
        int h = cc >> 6, d = cc & 63;
#pragma unroll
        for (int r = 0; r < 4; ++r) {
            int mrow = m0 + wm * 64 + r * 16 + quad * 4;
#pragma unroll
            for (int i = 0; i < 4; ++i) {
                float v = acc[r][c][i] + bv;
                int row = mrow + i;
                if (MODE == 3) {
                    ((float*)d0)[(size_t)row * 1024 + col] = v;
                } else {
                    int b = row >> 10, l = row & 1023;
                    unsigned short* base = (unsigned short*)(sect == 0 ? d0 : (sect == 1 ? d1 : d2));
                    bool isV = (sect == 2);
                    size_t off;
                    if (isV) off = (size_t)(b * 16 + h) * 65536 + (size_t)(l >> 5) * 2048 + d * 32 + (l & 31);
                    else off = ((size_t)(b * 16 + h) * 1024 + l) * 64 + d;
                    base[off] = f2bf(v);
                }
            }
        }
    }
}

// ---------------- flash attention v4: LDS-staged K/V tiles ----------------
// Qp,Kp: [b][h][1024][64] bf16; Vp: [b][h][32][64][32] bf16; mask: [b][1024] f32.
// Grid 1024 flat. qi interleaved so co-resident blocks have mixed causal lengths;
// bh constant mod 8 for XCD L2 locality. Block stages the 64-key K/V tile into
// LDS cooperatively (coalesced), register-prefetches the next tile.
__global__ __launch_bounds__(256) void k_flash_attn(const unsigned short* __restrict__ Qp,
                                                    const unsigned short* __restrict__ Kp,
                                                    const unsigned short* __restrict__ Vp,
                                                    const float* __restrict__ mask,
                                                    float* __restrict__ ctx,
                                                    int causal) {
    const int L = 1024, D = 1024;
    int f = blockIdx.x;
    int qi = ((f >> 3) + (f >> 7)) & 15;
    int bh = (f & 7) + ((f >> 7) << 3);
    int h = bh & 15, b = bh >> 4;
    int tid = threadIdx.x;
    int wave = tid >> 6, lane = tid & 63, quad = lane >> 4, l15 = lane & 15;
    int qbase = qi * 64 + wave * 16;

    __shared__ __align__(16) unsigned short Ks[4096];       // 8 KB, XOR-swizzled 16B blocks
    __shared__ __align__(16) unsigned short Vs[5120];       // 10 KB, 64B rows padded to 80B
    __shared__ unsigned short penb[1024];                   // 2 KB bf16 penalties
    __shared__ __align__(16) unsigned short Plds[4][1280];  // 10 KB (lo/hi halves per wave)

    {   // mask penalty -> LDS (bf16; exact 0 for m=1, -9984 for m=0: exp->0 either way)
        float4 mv = ((const float4*)(mask + b * L))[tid];
        ushortx4 pv;
        pv[0] = f2bf((1.0f - mv.x) * -10000.0f);
        pv[1] = f2bf((1.0f - mv.y) * -10000.0f);
        pv[2] = f2bf((1.0f - mv.z) * -10000.0f);
        pv[3] = f2bf((1.0f - mv.w) * -10000.0f);
        *((ushortx4*)penb + tid) = pv;
    }

    const unsigned short* Qh = Qp + ((size_t)(b * 16 + h) * 1024 + qbase) * 64;
    bf16x8 qf0 = *(const bf16x8*)(Qh + l15 * 64 + quad * 8);
    bf16x8 qf1 = *(const bf16x8*)(Qh + l15 * 64 + 32 + quad * 8);

    const char* Kh = (const char*)(Kp + (size_t)(b * 16 + h) * 65536);
    const char* Vh = (const char*)(Vp + (size_t)(b * 16 + h) * 65536);

    int ktiles = causal ? (qi + 1) : 16;   // block-uniform (barriers!)

    // staging dests (fixed per thread)
    char* Ksb = (char*)Ks;
    char* Vsb = (char*)Vs;
    int krow = tid >> 3, kblk = tid & 7;
    int kd0 = krow * 128 + ((kblk ^ (krow & 7)) << 4);
    int kd1 = kd0 + 32 * 128;               // (krow+32)&7 == krow&7
    int vd0 = (tid >> 2) * 80 + ((tid & 3) << 4);
    int vd1 = vd0 + 5120;

    // fragment read addresses (fixed per lane)
    int karA[4], karB[4];
#pragma unroll
    for (int r = 0; r < 4; ++r) {
        int row = r * 16 + l15;
        karA[r] = row * 128 + ((quad ^ (l15 & 7)) << 4);
        karB[r] = row * 128 + (((quad | 4) ^ (l15 & 7)) << 4);
    }
    int var_[8];
#pragma unroll
    for (int s = 0; s < 2; ++s)
#pragma unroll
        for (int fi = 0; fi < 4; ++fi)
            var_[s * 4 + fi] = s * 5120 + (fi * 16 + l15) * 80 + (quad << 4);

    floatx4 O[4] = {};
    float lsum[4] = {0.f, 0.f, 0.f, 0.f};
    unsigned short* pw_lo = &Plds[wave][0];
    unsigned short* pw_hi = &Plds[wave][640];

    // preload tile 0
    int4 ka0 = *(const int4*)(Kh + tid * 16);
    int4 ka1 = *(const int4*)(Kh + 4096 + tid * 16);
    int4 va0 = *(const int4*)(Vh + tid * 16);
    int4 va1 = *(const int4*)(Vh + 4096 + tid * 16);

    for (int kt = 0; kt < ktiles; ++kt) {
        *(int4*)(Ksb + kd0) = ka0;
        *(int4*)(Ksb + kd1) = ka1;
        *(int4*)(Vsb + vd0) = va0;
        *(int4*)(Vsb + vd1) = va1;
        __syncthreads();
        if (kt + 1 < ktiles) {   // prefetch next tile (lands during compute)
            const char* Kg = Kh + (size_t)(kt + 1) * 8192;
            const char* Vg = Vh + (size_t)(kt + 1) * 8192;
            ka0 = *(const int4*)(Kg + tid * 16);
            ka1 = *(const int4*)(Kg + 4096 + tid * 16);
            va0 = *(const int4*)(Vg + tid * 16);
            va1 = *(const int4*)(Vg + 4096 + tid * 16);
        }
        int k0 = kt * 64;

        // S = Q @ K^T  (16 q x 64 k), K frags from LDS
        floatx4 S0 = {}, S1 = {}, S2 = {}, S3 = {};
        {
            bf16x8 kA0 = *(const bf16x8*)(Ksb + karA[0]);
            bf16x8 kB0 = *(const bf16x8*)(Ksb + karB[0]);
            bf16x8 kA1 = *(const bf16x8*)(Ksb + karA[1]);
            bf16x8 kB1 = *(const bf16x8*)(Ksb + karB[1]);
            S0 = MFMA16(qf0, kA0, S0); S0 = MFMA16(qf1, kB0, S0);
            S1 = MFMA16(qf0, kA1, S1); S1 = MFMA16(qf1, kB1, S1);
            bf16x8 kA2 = *(const bf16x8*)(Ksb + karA[2]);
            bf16x8 kB2 = *(const bf16x8*)(Ksb + karB[2]);
            bf16x8 kA3 = *(const bf16x8*)(Ksb + karA[3]);
            bf16x8 kB3 = *(const bf16x8*)(Ksb + karB[3]);
            S2 = MFMA16(qf0, kA2, S2); S2 = MFMA16(qf1, kB2, S2);
            S3 = MFMA16(qf0, kA3, S3); S3 = MFMA16(qf1, kB3, S3);
        }

        float pen0 = bf2f(penb[k0 + l15]);
        float pen1 = bf2f(penb[k0 + 16 + l15]);
        float pen2 = bf2f(penb[k0 + 32 + l15]);
        float pen3 = bf2f(penb[k0 + 48 + l15]);

        // p = exp(S/8 + pen); no running max needed (bounded scores; masked -> 0)
#pragma unroll
        for (int i = 0; i < 4; ++i) {
            float e0, e1, e2, e3;
            if (causal) {
                int q = qbase + quad * 4 + i;
                e0 = ((k0 + l15) <= q) ? pen0 : -10000.0f;
                e1 = ((k0 + 16 + l15) <= q) ? pen1 : -10000.0f;
                e2 = ((k0 + 32 + l15) <= q) ? pen2 : -10000.0f;
                e3 = ((k0 + 48 + l15) <= q) ? pen3 : -10000.0f;
            } else {
                e0 = pen0; e1 = pen1; e2 = pen2; e3 = pen3;
            }
            float p0 = __expf(fmaf(S0[i], 0.125f, e0));
            float p1 = __expf(fmaf(S1[i], 0.125f, e1));
            float p2 = __expf(fmaf(S2[i], 0.125f, e2));
            float p3 = __expf(fmaf(S3[i], 0.125f, e3));
            lsum[i] += (p0 + p1) + (p2 + p3);
            int ro = (quad * 4 + i) * 40;
            pw_lo[ro + l15] = f2bf(p0);
            pw_lo[ro + 16 + l15] = f2bf(p1);
            pw_hi[ro + l15] = f2bf(p2);
            pw_hi[ro + 16 + l15] = f2bf(p3);
        }

        // PV: P (A-layout via per-wave LDS) x V frags from LDS
        bf16x8 pa_lo = *(const bf16x8*)(pw_lo + l15 * 40 + quad * 8);
        bf16x8 pa_hi = *(const bf16x8*)(pw_hi + l15 * 40 + quad * 8);
        bf16x8 v0 = *(const bf16x8*)(Vsb + var_[0]);
        bf16x8 v1 = *(const bf16x8*)(Vsb + var_[1]);
        bf16x8 v2 = *(const bf16x8*)(Vsb + var_[2]);
        bf16x8 v3 = *(const bf16x8*)(Vsb + var_[3]);
        O[0] = MFMA16(pa_lo, v0, O[0]);
        O[1] = MFMA16(pa_lo, v1, O[1]);
        O[2] = MFMA16(pa_lo, v2, O[2]);
        O[3] = MFMA16(pa_lo, v3, O[3]);
        bf16x8 v4 = *(const bf16x8*)(Vsb + var_[4]);
        bf16x8 v5 = *(const bf16x8*)(Vsb + var_[5]);
        bf16x8 v6 = *(const bf16x8*)(Vsb + var_[6]);
        bf16x8 v7 = *(const bf16x8*)(Vsb + var_[7]);
        O[0] = MFMA16(pa_hi, v4, O[0]);
        O[1] = MFMA16(pa_hi, v5, O[1]);
        O[2] = MFMA16(pa_hi, v6, O[2]);
        O[3] = MFMA16(pa_hi, v7, O[3]);
        __syncthreads();
    }

    // epilogue: ctx = O / l
#pragma unroll
    for (int i = 0; i < 4; ++i) {
        float l = lsum[i];
        l += __shfl_xor(l, 1);
        l += __shfl_xor(l, 2);
        l += __shfl_xor(l, 4);
        l += __shfl_xor(l, 8);
        float inv = 1.0f / l;
        int q = qbase + quad * 4 + i;
        float* op = ctx + ((size_t)(b * L + q)) * D + h * 64;
#pragma unroll
        for (int fi = 0; fi < 4; ++fi) op[fi * 16 + l15] = O[fi][i] * inv;
    }
}

// ---------------- add + layernorm (one block per 1024-row) ----------------
__global__ __launch_bounds__(256) void k_add_ln(const float* __restrict__ X,
                                                const float* __restrict__ Y,
                                                const float* __restrict__ w,
                                                const float* __restrict__ bvec,
                                                float* __restrict__ outf,
                                                unsigned short* __restrict__ outbf) {
    int row = blockIdx.x;
    int tid = threadIdx.x;
    float4 x = *((const float4*)(X + (size_t)row * 1024) + tid);
    float4 y = *((const float4*)(Y + (size_t)row * 1024) + tid);
    float v0 = x.x + y.x, v1 = x.y + y.y, v2 = x.z + y.z, v3 = x.w + y.w;
    float s = v0 + v1 + v2 + v3;
    float s2 = v0 * v0 + v1 * v1 + v2 * v2 + v3 * v3;
#pragma unroll
    for (int off = 32; off > 0; off >>= 1) {
        s += __shfl_xor(s, off);
        s2 += __shfl_xor(s2, off);
    }
    __shared__ float red[8];
    int wave = tid >> 6, lane = tid & 63;
    if (lane == 0) { red[wave] = s; red[4 + wave] = s2; }
    __syncthreads();
    s = red[0] + red[1] + red[2] + red[3];
    s2 = red[4] + red[5] + red[6] + red[7];
    float u = s * (1.0f / 1024.0f);
    float var = s2 * (1.0f / 1024.0f) - u * u;
    float r = 1.0f / sqrtf(fmaxf(var, 0.0f) + 1e-12f);
    float4 wv = *((const float4*)w + tid);
    float4 bv = *((const float4*)bvec + tid);
    float o0 = wv.x * (v0 - u) * r + bv.x;
    float o1 = wv.y * (v1 - u) * r + bv.y;
    float o2 = wv.z * (v2 - u) * r + bv.z;
    float o3 = wv.w * (v3 - u) * r + bv.w;
    float4 o = {o0, o1, o2, o3};
    *((float4*)(outf + (size_t)row * 1024) + tid) = o;
    if (outbf) {
        ushortx4 ob;
        ob[0] = f2bf(o0); ob[1] = f2bf(o1); ob[2] = f2bf(o2); ob[3] = f2bf(o3);
        *((ushortx4*)outbf + (size_t)row * 256 + tid) = ob;
    }
}

// ---------------- host ----------------
extern "C" void kernel_launch(void* const* d_in, const int* in_sizes, int n_in,
                              void* d_out, int out_size, void* d_ws, size_t ws_size,
                              hipStream_t stream) {
    (void)in_sizes; (void)n_in; (void)out_size; (void)ws_size;
    const float* dec = (const float*)d_in[0];
    const float* enc = (const float*)d_in[1];
    const float* dec_mask = (const float*)d_in[2];
    const float* enc_mask = (const float*)d_in[3];
    const float* b_saq = (const float*)d_in[11];
    const float* b_sak = (const float*)d_in[12];
    const float* b_sav = (const float*)d_in[13];
    const float* b_caq = (const float*)d_in[14];
    const float* b_cak = (const float*)d_in[15];
    const float* b_cav = (const float*)d_in[16];
    const float* b_out = (const float*)d_in[17];
    const float* n1_b = (const float*)d_in[18];
    const float* n2_b = (const float*)d_in[19];
    const float* oln_b = (const float*)d_in[20];
    const float* n1_w = (const float*)d_in[21];
    const float* n2_w = (const float*)d_in[22];
    const float* oln_w = (const float*)d_in[23];

    char* ws = (char*)d_ws;
    const size_t MB2 = 2097152;       // 1M bf16
    const size_t ACT_BF = 8388608;    // 4M bf16
    const size_t ACT_F32 = 16777216;  // 4M f32
    unsigned short* Wbf[7];
    for (int i = 0; i < 7; ++i) Wbf[i] = (unsigned short*)(ws + i * MB2);
    size_t off = 7 * MB2;
    unsigned short* Xbf = (unsigned short*)(ws + off); off += ACT_BF;   // Xbf,Ebf contiguous
    unsigned short* Ebf = (unsigned short*)(ws + off); off += ACT_BF;
    unsigned short* Abf = (unsigned short*)(ws + off); off += ACT_BF;
    unsigned short* Cbf = (unsigned short*)(ws + off); off += ACT_BF;
    unsigned short* Qp = (unsigned short*)(ws + off); off += ACT_BF;
    unsigned short* Kp = (unsigned short*)(ws + off); off += ACT_BF;
    unsigned short* Vp = (unsigned short*)(ws + off); off += ACT_BF;
    float* ctx = (float*)(ws + off); off += ACT_F32;   // reused as h
    float* a_f32 = (float*)(ws + off); off += ACT_F32;
    float* c_f32 = (float*)(ws + off); off += ACT_F32;
    float* h_f32 = ctx;
    float* outp = (float*)d_out;

    dim3 blk(256);
    dim3 attn_grid(1024);

    // converts: dec+enc in one dispatch; 7 weights in one dispatch (Wbf contiguous)
    Src2 s2; s2.p[0] = dec; s2.p[1] = enc;
    k_x2_to_bf16<<<dim3(4096), blk, 0, stream>>>(s2, Xbf);
    Src7 s7;
    for (int i = 0; i < 7; ++i) s7.p[i] = (const float*)d_in[4 + i];
    k_w7_to_bf16<<<dim3(3584), blk, 0, stream>>>(s7, Wbf[0]);

    // ---- self attention: fused QKV GEMM (N=3072) ----
    k_gemm_bias<0><<<dim3(32, 24), blk, 0, stream>>>(Xbf, Xbf, Wbf[0], b_saq, b_sak, b_sav,
                                                     Qp, Kp, Vp, 1024);
    k_flash_attn<<<attn_grid, blk, 0, stream>>>(Qp, Kp, Vp, dec_mask, ctx, 1);
    k_add_ln<<<dim3(4096), blk, 0, stream>>>(ctx, dec, n1_w, n1_b, a_f32, Abf);

    // ---- cross attention: fused Q(from A) + KV(from E) GEMM (N=3072) ----
    k_gemm_bias<4><<<dim3(32, 24), blk, 0, stream>>>(Abf, Ebf, Wbf[3], b_caq, b_cak, b_cav,
                                                     Qp, Kp, Vp, 1024);
    k_flash_attn<<<attn_grid, blk, 0, stream>>>(Qp, Kp, Vp, enc_mask, ctx, 0);
    k_add_ln<<<dim3(4096), blk, 0, stream>>>(a_f32, ctx, n2_w, n2_b, c_f32, Cbf);

    // ---- output dense + final LN ----
    k_gemm_bias<3><<<dim3(32, 8), blk, 0, stream>>>(Cbf, Cbf, Wbf[6], b_out, b_out, b_out,
                                                    h_f32, nullptr, nullptr, 1024);
    k_add_ln<<<dim3(4096), blk, 0, stream>>>(h_f32, c_f32, oln_w, oln_b, outp, (unsigned short*)nullptr);
}

// Round 5
// 337.584 us; speedup vs baseline: 1.7197x; 1.0396x over previous
//
#include <hip/hip_runtime.h>
#include <cstdint>
#include <cstddef>

// ---------------- types ----------------
typedef __bf16 bf16x8 __attribute__((ext_vector_type(8)));
typedef float  floatx4 __attribute__((ext_vector_type(4)));
typedef unsigned short ushortx8 __attribute__((ext_vector_type(8)));
typedef unsigned short ushortx4 __attribute__((ext_vector_type(4)));

#define MFMA16(a, b, c) __builtin_amdgcn_mfma_f32_16x16x32_bf16((a), (b), (c), 0, 0, 0)

__device__ inline unsigned short f2bf(float f) {
    unsigned int u = __float_as_uint(f);
    unsigned int r = (u + 0x7fffu + ((u >> 16) & 1u)) >> 16;
    return (unsigned short)r;
}

// ---------------- converts ----------------
struct Src2 { const float* p[2]; };
__global__ __launch_bounds__(256) void k_x2_to_bf16(Src2 s2, unsigned short* __restrict__ dst) {
    int i = blockIdx.x * 256 + threadIdx.x;   // 8 elems each; 524288 per tensor
    const float* src = s2.p[i >> 19];
    int off = i & 524287;
    const float4* s = (const float4*)src + (size_t)off * 2;
    float4 x0 = s[0], x1 = s[1];
    ushortx8 o;
    o[0] = f2bf(x0.x); o[1] = f2bf(x0.y); o[2] = f2bf(x0.z); o[3] = f2bf(x0.w);
    o[4] = f2bf(x1.x); o[5] = f2bf(x1.y); o[6] = f2bf(x1.z); o[7] = f2bf(x1.w);
    *((ushortx8*)dst + i) = o;
}
struct Src7 { const float* p[7]; };
__global__ __launch_bounds__(256) void k_w7_to_bf16(Src7 s7, unsigned short* __restrict__ dst) {
    int i = blockIdx.x * 256 + threadIdx.x;   // 131072 i-units per weight
    const float* src = s7.p[i >> 17];
    int off = i & 131071;
    const float4* s = (const float4*)src + (size_t)off * 2;
    float4 x0 = s[0], x1 = s[1];
    ushortx8 o;
    o[0] = f2bf(x0.x); o[1] = f2bf(x0.y); o[2] = f2bf(x0.z); o[3] = f2bf(x0.w);
    o[4] = f2bf(x1.x); o[5] = f2bf(x1.y); o[6] = f2bf(x1.z); o[7] = f2bf(x1.w);
    *((ushortx8*)dst + i) = o;
}

// ---------------- GEMM: C[M][Nc] = A[M][K] @ W[Nc][K]^T + bias ----------------
// MODE 0: fused QKV packs (A for all sections)
// MODE 3: f32 row-major
// MODE 4: fused cross QKV (sect 0 uses A, sects 1-2 use A2)
// Pack layouts: Q/K[b][h][l][64] bf16;
// V[b][h][l/32][d(64)][perm(l%32)] bf16 with perm(k) = ((k&15)<<1)|(k>>4)
// (k-interleave matches the flash kernel's P-pair packing order).
template <int MODE>
__global__ __launch_bounds__(256) void k_gemm_bias(const unsigned short* __restrict__ A,
                                                   const unsigned short* __restrict__ A2,
                                                   const unsigned short* __restrict__ W,
                                                   const float* __restrict__ bias0,
                                                   const float* __restrict__ bias1,
                                                   const float* __restrict__ bias2,
                                                   void* __restrict__ d0,
                                                   void* __restrict__ d1,
                                                   void* __restrict__ d2,
                                                   int K) {
    __shared__ __align__(16) unsigned short As[128 * 32];
    __shared__ __align__(16) unsigned short Bs[128 * 32];
    const int tid = threadIdx.x;
    const int wave = tid >> 6, lane = tid & 63;
    const int quad = lane >> 4, l15 = lane & 15;
    const int wm = wave >> 1, wn = wave & 1;
    const int m0 = blockIdx.x * 128, n0 = blockIdx.y * 128;
    const int sect_blk = n0 >> 10;

    const unsigned short* Ause = (MODE == 4 && sect_blk != 0) ? A2 : A;

    const size_t rowbytes = (size_t)K * 2;
    const int idx0 = tid, idx1 = 256 + tid;
    const int rA0 = idx0 >> 2, cb0 = (idx0 & 3) << 4;
    const int rA1 = idx1 >> 2, cb1 = (idx1 & 3) << 4;
    const char* gA0 = (const char*)Ause + (size_t)(m0 + rA0) * rowbytes + cb0;
    const char* gA1 = (const char*)Ause + (size_t)(m0 + rA1) * rowbytes + cb1;
    const char* gB0 = (const char*)W + (size_t)(n0 + rA0) * rowbytes + cb0;
    const char* gB1 = (const char*)W + (size_t)(n0 + rA1) * rowbytes + cb1;

    int4 pa0 = *(const int4*)gA0, pa1 = *(const int4*)gA1;
    int4 pb0 = *(const int4*)gB0, pb1 = *(const int4*)gB1;

    floatx4 acc[4][4] = {};

    const int KT = K >> 5;
    for (int kt = 0; kt < KT; ++kt) {
        __syncthreads();
        ((int4*)As)[idx0] = pa0; ((int4*)As)[idx1] = pa1;
        ((int4*)Bs)[idx0] = pb0; ((int4*)Bs)[idx1] = pb1;
        __syncthreads();
        if (kt + 1 < KT) {
            gA0 += 64; gA1 += 64; gB0 += 64; gB1 += 64;
            pa0 = *(const int4*)gA0; pa1 = *(const int4*)gA1;
            pb0 = *(const int4*)gB0; pb1 = *(const int4*)gB1;
        }
        bf16x8 af[4], bfr[4];
        const char* Asb = (const char*)As;
        const char* Bsb = (const char*)Bs;
#pragma unroll
        for (int r = 0; r < 4; ++r)
            af[r] = *(const bf16x8*)(Asb + ((wm * 64 + r * 16 + l15) * 64 + quad * 16));
#pragma unroll
        for (int c = 0; c < 4; ++c)
            bfr[c] = *(const bf16x8*)(Bsb + ((wn * 64 + c * 16 + l15) * 64 + quad * 16));
#pragma unroll
        for (int r = 0; r < 4; ++r)
#pragma unroll
            for (int c = 0; c < 4; ++c)
                acc[r][c] = MFMA16(af[r], bfr[c], acc[r][c]);
    }

    // epilogue: C row = quad*4+i, col = l15
#pragma unroll
    for (int c = 0; c < 4; ++c) {
        int col = n0 + wn * 64 + c * 16 + l15;
        int sect = col >> 10, cc = col & 1023;
        float bv;
        if (MODE == 3) bv = bias0[col];
        else bv = (sect == 0 ? bias0 : (sect == 1 ? bias1 : bias2))[cc];
        int h = cc >> 6, d = cc & 63;
#pragma unroll
        for (int r = 0; r < 4; ++r) {
            int mrow = m0 + wm * 64 + r * 16 + quad * 4;
#pragma unroll
            for (int i = 0; i < 4; ++i) {
                float v = acc[r][c][i] + bv;
                int row = mrow + i;
                if (MODE == 3) {
                    ((float*)d0)[(size_t)row * 1024 + col] = v;
                } else {
                    int b = row >> 10, l = row & 1023;
                    unsigned short* base = (unsigned short*)(sect == 0 ? d0 : (sect == 1 ? d1 : d2));
                    bool isV = (sect == 2);
                    size_t off;
                    if (isV) {
                        int kk = l & 31;
                        int kperm = ((kk & 15) << 1) | (kk >> 4);
                        off = (size_t)(b * 16 + h) * 65536 + (size_t)(l >> 5) * 2048 + d * 32 + kperm;
                    } else {
                        off = ((size_t)(b * 16 + h) * 1024 + l) * 64 + d;
                    }
                    base[off] = f2bf(v);
                }
            }
        }
    }
}

// ---------------- flash attention v5 ----------------
// Qp,Kp: [b][h][1024][64] bf16; Vp: [b][h][32][64][perm32] bf16; mask: [b][1024] f32.
// Grid 512: block = 128 q rows (4 waves x 32q), qt interleaved for causal balance,
// bh constant mod 8 for XCD L2 locality. K/V tiles (64 keys) LDS-staged cooperatively.
// Softmax: exp2 with pre-scaled penalties, no running max (bounded scores),
// deferred l-reduction, P packed to bf16 pairs via v_perm (k-interleaved to match Vp).
__global__ __launch_bounds__(256, 2) void k_flash_attn(const unsigned short* __restrict__ Qp,
                                                       const unsigned short* __restrict__ Kp,
                                                       const unsigned short* __restrict__ Vp,
                                                       const float* __restrict__ mask,
                                                       float* __restrict__ ctx,
                                                       int causal) {
    const int L = 1024, D = 1024;
    const float SC = 0.18033688011112042f;      // 0.125 * log2(e)
    int f = blockIdx.x;
    int g = f >> 6;
    int bh = (f & 7) + (g << 3);
    int qt = ((f >> 3) + g) & 7;
    int h = bh & 15, b = bh >> 4;
    int tid = threadIdx.x;
    int wave = tid >> 6, lane = tid & 63, quad = lane >> 4, l15 = lane & 15;
    int qbase = qt * 128 + wave * 32;

    __shared__ __align__(16) unsigned short Ks[4096];   // 8 KB: 64 keys x 64d, XOR-swizzled
    __shared__ __align__(16) unsigned short Vs[5120];   // 10 KB: 2 x 64d x 32k, rows padded 80B
    __shared__ float penf[1024];                        // 4 KB: (1-m)*-10000*log2e
    __shared__ __align__(16) unsigned short Plds[4 * 1280];  // 10 KB: per-wave P buffer

    {   // mask penalty, pre-scaled for exp2
        float4 mv = ((const float4*)(mask + b * L))[tid];
        float4 pv;
        pv.x = (1.0f - mv.x) * -14426.950408889634f;
        pv.y = (1.0f - mv.y) * -14426.950408889634f;
        pv.z = (1.0f - mv.z) * -14426.950408889634f;
        pv.w = (1.0f - mv.w) * -14426.950408889634f;
        ((float4*)penf)[tid] = pv;
    }

    // Q fragments: 32 q rows per wave = 2 halves x 2 k-chunks
    const unsigned short* Qh = Qp + ((size_t)(b * 16 + h) * 1024 + qbase) * 64;
    bf16x8 qf[2][2];
#pragma unroll
    for (int qh = 0; qh < 2; ++qh) {
        qf[qh][0] = *(const bf16x8*)(Qh + (qh * 16 + l15) * 64 + quad * 8);
        qf[qh][1] = *(const bf16x8*)(Qh + (qh * 16 + l15) * 64 + 32 + quad * 8);
    }

    const char* Kh = (const char*)(Kp + (size_t)(b * 16 + h) * 65536);
    const char* Vh = (const char*)(Vp + (size_t)(b * 16 + h) * 65536);

    int ktiles = causal ? (2 * qt + 2) : 16;   // block-uniform

    // staging dests
    char* Ksb = (char*)Ks;
    char* Vsb = (char*)Vs;
    int krow = tid >> 3, kblk = tid & 7;
    int kd0 = krow * 128 + ((kblk ^ (krow & 7)) << 4);
    int kd1 = kd0 + 32 * 128;
    int vd0 = (tid >> 2) * 80 + ((tid & 3) << 4);
    int vd1 = vd0 + 5120;

    // fragment read offsets
    int karA[4], karB[4];
#pragma unroll
    for (int r = 0; r < 4; ++r) {
        int row = r * 16 + l15;
        karA[r] = row * 128 + ((quad ^ (l15 & 7)) << 4);
        karB[r] = row * 128 + (((quad | 4) ^ (l15 & 7)) << 4);
    }
    int var_[8];
#pragma unroll
    for (int s = 0; s < 2; ++s)
#pragma unroll
        for (int fi = 0; fi < 4; ++fi)
            var_[s * 4 + fi] = s * 5120 + (fi * 16 + l15) * 80 + (quad << 4);

    floatx4 O[2][4] = {};
    float lsum[2][4] = {};
    unsigned short* pw = &Plds[wave * 1280];
    unsigned int* pw32 = (unsigned int*)pw;

    // preload tile 0
    int4 ka0 = *(const int4*)(Kh + tid * 16);
    int4 ka1 = *(const int4*)(Kh + 4096 + tid * 16);
    int4 va0 = *(const int4*)(Vh + tid * 16);
    int4 va1 = *(const int4*)(Vh + 4096 + tid * 16);

    for (int kt = 0; kt < ktiles; ++kt) {
        *(int4*)(Ksb + kd0) = ka0;
        *(int4*)(Ksb + kd1) = ka1;
        *(int4*)(Vsb + vd0) = va0;
        *(int4*)(Vsb + vd1) = va1;
        __syncthreads();
        if (kt + 1 < ktiles) {
            const char* Kg = Kh + (size_t)(kt + 1) * 8192;
            const char* Vg = Vh + (size_t)(kt + 1) * 8192;
            ka0 = *(const int4*)(Kg + tid * 16);
            ka1 = *(const int4*)(Kg + 4096 + tid * 16);
            va0 = *(const int4*)(Vg + tid * 16);
            va1 = *(const int4*)(Vg + 4096 + tid * 16);
        }
        int k0 = kt * 64;

        if (!(causal && k0 > qbase + 31)) {   // wave-uniform: any visible keys?
            // K fragments (shared by both q-halves)
            bf16x8 kA[4], kB[4];
#pragma unroll
            for (int r = 0; r < 4; ++r) {
                kA[r] = *(const bf16x8*)(Ksb + karA[r]);
                kB[r] = *(const bf16x8*)(Ksb + karB[r]);
            }
            // V fragments (read once, used by both q-halves)
            bf16x8 vv[8];
#pragma unroll
            for (int s = 0; s < 8; ++s) vv[s] = *(const bf16x8*)(Vsb + var_[s]);
            // penalties
            float pr0 = penf[k0 + l15];
            float pr1 = penf[k0 + 16 + l15];
            float pr2 = penf[k0 + 32 + l15];
            float pr3 = penf[k0 + 48 + l15];

#pragma unroll
            for (int qh = 0; qh < 2; ++qh) {
                int qlo = qbase + qh * 16;
                if (causal && k0 > qlo + 15) continue;      // this half fully masked
                bool boundary = causal && (k0 + 63 > qlo);  // needs per-element check

                floatx4 S0 = {}, S1 = {}, S2 = {}, S3 = {};
                S0 = MFMA16(qf[qh][0], kA[0], S0); S0 = MFMA16(qf[qh][1], kB[0], S0);
                S1 = MFMA16(qf[qh][0], kA[1], S1); S1 = MFMA16(qf[qh][1], kB[1], S1);
                S2 = MFMA16(qf[qh][0], kA[2], S2); S2 = MFMA16(qf[qh][1], kB[2], S2);
                S3 = MFMA16(qf[qh][0], kA[3], S3); S3 = MFMA16(qf[qh][1], kB[3], S3);

                int qrow = qlo + quad * 4;
#pragma unroll
                for (int i = 0; i < 4; ++i) {
                    float x0 = fmaf(S0[i], SC, pr0);
                    float x1 = fmaf(S1[i], SC, pr1);
                    float x2 = fmaf(S2[i], SC, pr2);
                    float x3 = fmaf(S3[i], SC, pr3);
                    if (boundary) {
                        int q = qrow + i;
                        x0 = ((k0 + l15) <= q) ? x0 : -50000.0f;
                        x1 = ((k0 + 16 + l15) <= q) ? x1 : -50000.0f;
                        x2 = ((k0 + 32 + l15) <= q) ? x2 : -50000.0f;
                        x3 = ((k0 + 48 + l15) <= q) ? x3 : -50000.0f;
                    }
                    float p0 = __builtin_amdgcn_exp2f(x0);
                    float p1 = __builtin_amdgcn_exp2f(x1);
                    float p2 = __builtin_amdgcn_exp2f(x2);
                    float p3 = __builtin_amdgcn_exp2f(x3);
                    lsum[qh][i] += (p0 + p1) + (p2 + p3);
                    // pack to bf16 pairs (round-half-up) in k-interleaved order
                    unsigned r0 = __float_as_uint(p0) + 0x8000u;
                    unsigned r1 = __float_as_uint(p1) + 0x8000u;
                    unsigned r2 = __float_as_uint(p2) + 0x8000u;
                    unsigned r3 = __float_as_uint(p3) + 0x8000u;
                    unsigned plo = __builtin_amdgcn_perm(r1, r0, 0x07060302u);
                    unsigned phi = __builtin_amdgcn_perm(r3, r2, 0x07060302u);
                    int ro = (quad * 4 + i) * 20;
                    pw32[ro + l15] = plo;
                    pw32[320 + ro + l15] = phi;
                }
                bf16x8 pa_lo = *(const bf16x8*)(pw + l15 * 40 + quad * 8);
                bf16x8 pa_hi = *(const bf16x8*)(pw + 640 + l15 * 40 + quad * 8);
                O[qh][0] = MFMA16(pa_lo, vv[0], O[qh][0]);
                O[qh][1] = MFMA16(pa_lo, vv[1], O[qh][1]);
                O[qh][2] = MFMA16(pa_lo, vv[2], O[qh][2]);
                O[qh][3] = MFMA16(pa_lo, vv[3], O[qh][3]);
                O[qh][0] = MFMA16(pa_hi, vv[4], O[qh][0]);
                O[qh][1] = MFMA16(pa_hi, vv[5], O[qh][1]);
                O[qh][2] = MFMA16(pa_hi, vv[6], O[qh][2]);
                O[qh][3] = MFMA16(pa_hi, vv[7], O[qh][3]);
            }
        }
        __syncthreads();
    }

    // epilogue: ctx = O / l
#pragma unroll
    for (int qh = 0; qh < 2; ++qh)
#pragma unroll
        for (int i = 0; i < 4; ++i) {
            float l = lsum[qh][i];
            l += __shfl_xor(l, 1);
            l += __shfl_xor(l, 2);
            l += __shfl_xor(l, 4);
            l += __shfl_xor(l, 8);
            float inv = 1.0f / l;
            int q = qbase + qh * 16 + quad * 4 + i;
            float* op = ctx + ((size_t)(b * L + q)) * D + h * 64;
#pragma unroll
            for (int fi = 0; fi < 4; ++fi) op[fi * 16 + l15] = O[qh][fi][i] * inv;
        }
}

// ---------------- add + layernorm (one block per 1024-row) ----------------
__global__ __launch_bounds__(256) void k_add_ln(const float* __restrict__ X,
                                                const float* __restrict__ Y,
                                                const float* __restrict__ w,
                                                const float* __restrict__ bvec,
                                                float* __restrict__ outf,
                                                unsigned short* __restrict__ outbf) {
    int row = blockIdx.x;
    int tid = threadIdx.x;
    float4 x = *((const float4*)(X + (size_t)row * 1024) + tid);
    float4 y = *((const float4*)(Y + (size_t)row * 1024) + tid);
    float v0 = x.x + y.x, v1 = x.y + y.y, v2 = x.z + y.z, v3 = x.w + y.w;
    float s = v0 + v1 + v2 + v3;
    float s2 = v0 * v0 + v1 * v1 + v2 * v2 + v3 * v3;
#pragma unroll
    for (int off = 32; off > 0; off >>= 1) {
        s += __shfl_xor(s, off);
        s2 += __shfl_xor(s2, off);
    }
    __shared__ float red[8];
    int wave = tid >> 6, lane = tid & 63;
    if (lane == 0) { red[wave] = s; red[4 + wave] = s2; }
    __syncthreads();
    s = red[0] + red[1] + red[2] + red[3];
    s2 = red[4] + red[5] + red[6] + red[7];
    float u = s * (1.0f / 1024.0f);
    float var = s2 * (1.0f / 1024.0f) - u * u;
    float r = 1.0f / sqrtf(fmaxf(var, 0.0f) + 1e-12f);
    float4 wv = *((const float4*)w + tid);
    float4 bv = *((const float4*)bvec + tid);
    float o0 = wv.x * (v0 - u) * r + bv.x;
    float o1 = wv.y * (v1 - u) * r + bv.y;
    float o2 = wv.z * (v2 - u) * r + bv.z;
    float o3 = wv.w * (v3 - u) * r + bv.w;
    float4 o = {o0, o1, o2, o3};
    *((float4*)(outf + (size_t)row * 1024) + tid) = o;
    if (outbf) {
        ushortx4 ob;
        ob[0] = f2bf(o0); ob[1] = f2bf(o1); ob[2] = f2bf(o2); ob[3] = f2bf(o3);
        *((ushortx4*)outbf + (size_t)row * 256 + tid) = ob;
    }
}

// ---------------- host ----------------
extern "C" void kernel_launch(void* const* d_in, const int* in_sizes, int n_in,
                              void* d_out, int out_size, void* d_ws, size_t ws_size,
                              hipStream_t stream) {
    (void)in_sizes; (void)n_in; (void)out_size; (void)ws_size;
    const float* dec = (const float*)d_in[0];
    const float* enc = (const float*)d_in[1];
    const float* dec_mask = (const float*)d_in[2];
    const float* enc_mask = (const float*)d_in[3];
    const float* b_saq = (const float*)d_in[11];
    const float* b_sak = (const float*)d_in[12];
    const float* b_sav = (const float*)d_in[13];
    const float* b_caq = (const float*)d_in[14];
    const float* b_cak = (const float*)d_in[15];
    const float* b_cav = (const float*)d_in[16];
    const float* b_out = (const float*)d_in[17];
    const float* n1_b = (const float*)d_in[18];
    const float* n2_b = (const float*)d_in[19];
    const float* oln_b = (const float*)d_in[20];
    const float* n1_w = (const float*)d_in[21];
    const float* n2_w = (const float*)d_in[22];
    const float* oln_w = (const float*)d_in[23];

    char* ws = (char*)d_ws;
    const size_t MB2 = 2097152;       // 1M bf16
    const size_t ACT_BF = 8388608;    // 4M bf16
    const size_t ACT_F32 = 16777216;  // 4M f32
    unsigned short* Wbf[7];
    for (int i = 0; i < 7; ++i) Wbf[i] = (unsigned short*)(ws + i * MB2);
    size_t off = 7 * MB2;
    unsigned short* Xbf = (unsigned short*)(ws + off); off += ACT_BF;   // Xbf,Ebf contiguous
    unsigned short* Ebf = (unsigned short*)(ws + off); off += ACT_BF;
    unsigned short* Abf = (unsigned short*)(ws + off); off += ACT_BF;
    unsigned short* Cbf = (unsigned short*)(ws + off); off += ACT_BF;
    unsigned short* Qp = (unsigned short*)(ws + off); off += ACT_BF;
    unsigned short* Kp = (unsigned short*)(ws + off); off += ACT_BF;
    unsigned short* Vp = (unsigned short*)(ws + off); off += ACT_BF;
    float* ctx = (float*)(ws + off); off += ACT_F32;   // reused as h
    float* a_f32 = (float*)(ws + off); off += ACT_F32;
    float* c_f32 = (float*)(ws + off); off += ACT_F32;
    float* h_f32 = ctx;
    float* outp = (float*)d_out;

    dim3 blk(256);
    dim3 attn_grid(512);

    Src2 s2; s2.p[0] = dec; s2.p[1] = enc;
    k_x2_to_bf16<<<dim3(4096), blk, 0, stream>>>(s2, Xbf);
    Src7 s7;
    for (int i = 0; i < 7; ++i) s7.p[i] = (const float*)d_in[4 + i];
    k_w7_to_bf16<<<dim3(3584), blk, 0, stream>>>(s7, Wbf[0]);

    // ---- self attention: fused QKV GEMM (N=3072) ----
    k_gemm_bias<0><<<dim3(32, 24), blk, 0, stream>>>(Xbf, Xbf, Wbf[0], b_saq, b_sak, b_sav,
                                                     Qp, Kp, Vp, 1024);
    k_flash_attn<<<attn_grid, blk, 0, stream>>>(Qp, Kp, Vp, dec_mask, ctx, 1);
    k_add_ln<<<dim3(4096), blk, 0, stream>>>(ctx, dec, n1_w, n1_b, a_f32, Abf);

    // ---- cross attention: fused Q(from A) + KV(from E) GEMM (N=3072) ----
    k_gemm_bias<4><<<dim3(32, 24), blk, 0, stream>>>(Abf, Ebf, Wbf[3], b_caq, b_cak, b_cav,
                                                     Qp, Kp, Vp, 1024);
    k_flash_attn<<<attn_grid, blk, 0, stream>>>(Qp, Kp, Vp, enc_mask, ctx, 0);
    k_add_ln<<<dim3(4096), blk, 0, stream>>>(a_f32, ctx, n2_w, n2_b, c_f32, Cbf);

    // ---- output dense + final LN ----
    k_gemm_bias<3><<<dim3(32, 8), blk, 0, stream>>>(Cbf, Cbf, Wbf[6], b_out, b_out, b_out,
                                                    h_f32, nullptr, nullptr, 1024);
    k_add_ln<<<dim3(4096), blk, 0, stream>>>(h_f32, c_f32, oln_w, oln_b, outp, (unsigned short*)nullptr);
}